// Round 3
// baseline (386.023 us; speedup 1.0000x reference)
//
#include <hip/hip_runtime.h>
#include <hip/hip_bf16.h>
#include <cstdint>
#include <cstddef>

typedef __bf16 bf16_t;
typedef bf16_t bf16x8 __attribute__((ext_vector_type(8)));
typedef bf16_t bf16x4 __attribute__((ext_vector_type(4)));
typedef float f32x4 __attribute__((ext_vector_type(4)));

#define NB 8
#define NT 1024
#define NC 1024
#define NH 16
#define ND 64
#define NTP 64

// ---------------- cast fp32 -> bf16 (vectorized x4) ----------------
__global__ __launch_bounds__(256) void k_cast_bf16(const float* __restrict__ src,
                                                   bf16_t* __restrict__ dst, int n4) {
    int i = blockIdx.x * 256 + threadIdx.x;
    if (i < n4) {
        float4 f = ((const float4*)src)[i];
        bf16x4 o;
        o[0] = (bf16_t)f.x; o[1] = (bf16_t)f.y; o[2] = (bf16_t)f.z; o[3] = (bf16_t)f.w;
        ((bf16x4*)dst)[i] = o;
    }
}

// ---------------- transpose + cast: src (K,N) fp32 -> dst (N,K) bf16 ----------------
__global__ __launch_bounds__(256) void k_transpose_cast(const float* __restrict__ src,
                                                        bf16_t* __restrict__ dst,
                                                        int K, int N) {
    __shared__ float tile[32][33];
    int nt = blockIdx.x, kt = blockIdx.y;
    int tx = threadIdx.x & 31;
    int ty = threadIdx.x >> 5;  // 0..7
#pragma unroll
    for (int i = 0; i < 4; i++) {
        int r = ty + i * 8;
        tile[r][tx] = src[(size_t)(kt * 32 + r) * N + nt * 32 + tx];
    }
    __syncthreads();
#pragma unroll
    for (int i = 0; i < 4; i++) {
        int r = ty + i * 8;
        dst[(size_t)(nt * 32 + r) * K + kt * 32 + tx] = (bf16_t)tile[tx][r];
    }
}

// ------- per-head V transpose into TILE-CONTIGUOUS layout -------
// dst tile (bh, tt) is 64x64 (d-major): dst[((bh*(T/64)+tt)*64 + d)*64 + t%64]
__global__ __launch_bounds__(256) void k_vT(const bf16_t* __restrict__ src,
                                            bf16_t* __restrict__ dst, int T) {
    __shared__ bf16_t tile[32][33];
    const int bh = blockIdx.z;
    const int b = bh >> 4, h = bh & 15;
    const int t0 = blockIdx.x * 32, d0 = blockIdx.y * 32;
    const int tx = threadIdx.x & 31;
    const int ty = threadIdx.x >> 5;  // 0..7
#pragma unroll
    for (int i = 0; i < 4; i++) {
        int r = ty + i * 8;  // t offset
        tile[r][tx] = src[(size_t)(b * T + t0 + r) * 3072 + 2 * NC + h * 64 + d0 + tx];
    }
    __syncthreads();
    const size_t tileBase = ((size_t)bh * (T / 64) + (t0 >> 6)) * 64 * 64;
#pragma unroll
    for (int i = 0; i < 4; i++) {
        int r = ty + i * 8;  // d offset
        dst[tileBase + (size_t)(d0 + r) * 64 + (t0 & 63) + tx] = tile[tx][r];
    }
}

// ---------------- GEMM: C(M,N) = A(M,K) @ BT(N,K)^T + bias ----------------
// 128x128 tile, BK=64, reg-staged global->LDS with padded stride 72.
// (gload_lds/linear variant regressed at K=1024: vmcnt(0) drain dominates a
//  16-iteration K-loop; reg-staging lets the compiler pipeline across barriers.)
template <bool OUT_F32>
__global__ __launch_bounds__(256) void k_gemm_bt(const bf16_t* __restrict__ A,
                                                 const bf16_t* __restrict__ BT,
                                                 const float* __restrict__ bias,
                                                 void* __restrict__ Cout,
                                                 int M, int N, int K) {
    __shared__ bf16_t As[128 * 72];
    __shared__ bf16_t Bs[128 * 72];
    const int tid = threadIdx.x;
    const int lane = tid & 63;
    const int wave = tid >> 6;
    const int quad = lane >> 4;
    const int l15 = lane & 15;
    const int wm = (wave >> 1) * 64;
    const int wn = (wave & 1) * 64;
    const size_t rowA0 = (size_t)blockIdx.y * 128;
    const size_t colB0 = (size_t)blockIdx.x * 128;

    const f32x4 fz = {0.f, 0.f, 0.f, 0.f};
    f32x4 acc[4][4];
#pragma unroll
    for (int i = 0; i < 4; i++)
#pragma unroll
        for (int j = 0; j < 4; j++) acc[i][j] = fz;

    for (int k0 = 0; k0 < K; k0 += 64) {
        __syncthreads();
#pragma unroll
        for (int i = 0; i < 4; i++) {
            int c = tid + i * 256;
            int r = c >> 3;
            int kc = (c & 7) * 8;
            uint4 av = *(const uint4*)(A + (rowA0 + r) * K + k0 + kc);
            *(uint4*)(&As[r * 72 + kc]) = av;
            uint4 bv = *(const uint4*)(BT + (colB0 + r) * K + k0 + kc);
            *(uint4*)(&Bs[r * 72 + kc]) = bv;
        }
        __syncthreads();
#pragma unroll
        for (int kk = 0; kk < 2; kk++) {
            bf16x8 af[4], bfr[4];
#pragma unroll
            for (int i = 0; i < 4; i++)
                af[i] = *(const bf16x8*)(&As[(wm + i * 16 + l15) * 72 + kk * 32 + quad * 8]);
#pragma unroll
            for (int j = 0; j < 4; j++)
                bfr[j] = *(const bf16x8*)(&Bs[(wn + j * 16 + l15) * 72 + kk * 32 + quad * 8]);
#pragma unroll
            for (int i = 0; i < 4; i++)
#pragma unroll
                for (int j = 0; j < 4; j++)
                    acc[i][j] = __builtin_amdgcn_mfma_f32_16x16x32_bf16(af[i], bfr[j], acc[i][j], 0, 0, 0);
        }
    }
#pragma unroll
    for (int i = 0; i < 4; i++) {
        size_t row = rowA0 + wm + i * 16 + quad * 4;
#pragma unroll
        for (int j = 0; j < 4; j++) {
            int col = (int)colB0 + wn + j * 16 + l15;
            float bv = bias[col];
#pragma unroll
            for (int r = 0; r < 4; r++) {
                float v = acc[i][j][r] + bv;
                if (OUT_F32)
                    ((float*)Cout)[(row + r) * (size_t)N + col] = v;
                else
                    ((bf16_t*)Cout)[(row + r) * (size_t)N + col] = (bf16_t)v;
            }
        }
    }
}

// ---------------- fused dual-softmax causal attention ----------------
// v9: V is NOT staged in LDS. vp is pre-transposed into exact B-fragment
// layout, so each PV fragment is a contiguous 16B global load (L2-resident:
// 128 KB V per (b,h)). V-frag loads for tile t are issued right after tile
// t-1's PV consumed the old frags -> one QK+softmax phase covers L2 latency.
// K stays LDS double-buffered (4-wave reuse; global K frags would be 16
// scattered rows). LDS 46->27.6 KB => 5 blocks/CU.

#define LOADK(KB)                                                         \
    rk0 = *(const uint4*)((KB) + (size_t)srow * 3072 + scol);             \
    rk1 = *(const uint4*)((KB) + (size_t)(srow + 32) * 3072 + scol);

#define STAGEK(KS)                                        \
    *(uint4*)(&(KS)[srow * 72 + scol]) = rk0;             \
    *(uint4*)(&(KS)[(srow + 32) * 72 + scol]) = rk1;

#define LOADV(VB)                                                               \
    vf0 = *(const bf16x8*)((VB) + (size_t)(0 * 16 + l15) * 64 + quad * 8);      \
    vf1 = *(const bf16x8*)((VB) + (size_t)(0 * 16 + l15) * 64 + 32 + quad * 8); \
    vf2 = *(const bf16x8*)((VB) + (size_t)(1 * 16 + l15) * 64 + quad * 8);      \
    vf3 = *(const bf16x8*)((VB) + (size_t)(1 * 16 + l15) * 64 + 32 + quad * 8); \
    vf4 = *(const bf16x8*)((VB) + (size_t)(2 * 16 + l15) * 64 + quad * 8);      \
    vf5 = *(const bf16x8*)((VB) + (size_t)(2 * 16 + l15) * 64 + 32 + quad * 8); \
    vf6 = *(const bf16x8*)((VB) + (size_t)(3 * 16 + l15) * 64 + quad * 8);      \
    vf7 = *(const bf16x8*)((VB) + (size_t)(3 * 16 + l15) * 64 + 32 + quad * 8);

#define QK(KS, Sj, j)                                                                  \
    Sj = __builtin_amdgcn_mfma_f32_16x16x32_bf16(                                      \
        aq0, *(const bf16x8*)(&(KS)[((j) * 16 + l15) * 72 + quad * 8]), Sj, 0, 0, 0);  \
    Sj = __builtin_amdgcn_mfma_f32_16x16x32_bf16(                                      \
        aq1, *(const bf16x8*)(&(KS)[((j) * 16 + l15) * 72 + 32 + quad * 8]), Sj, 0, 0, 0);

#define EXPJ(Sj, j, DIAG, LACC)                                         \
    {                                                                   \
        const int n_ = (j) * 16 + l15;                                  \
        _Pragma("unroll") for (int r_ = 0; r_ < 4; r_++) {              \
            float p_ = __expf(Sj[r_] * scale);                          \
            if ((DIAG) && n_ > wave * 16 + quad * 4 + r_) p_ = 0.f;     \
            Sj[r_] = p_;                                                \
            LACC[r_] += p_;                                             \
        }                                                               \
    }

#define PSTORE(Sj, j)                                                   \
    _Pragma("unroll") for (int r_ = 0; r_ < 4; r_++)                    \
        P[(quad * 4 + r_) * 72 + (j) * 16 + l15] = (bf16_t)Sj[r_];

#define PVr(Oj, Vlo, Vhi)                                                         \
    Oj = __builtin_amdgcn_mfma_f32_16x16x32_bf16(ap0, Vlo, Oj, 0, 0, 0);          \
    Oj = __builtin_amdgcn_mfma_f32_16x16x32_bf16(ap1, Vhi, Oj, 0, 0, 0);

#define PROC(KS, DIAG, LACC, O0, O1, O2, O3)                            \
    {                                                                   \
        f32x4 S0 = fz, S1 = fz, S2 = fz, S3 = fz;                       \
        QK(KS, S0, 0) QK(KS, S1, 1) QK(KS, S2, 2) QK(KS, S3, 3)         \
        EXPJ(S0, 0, DIAG, LACC) EXPJ(S1, 1, DIAG, LACC)                 \
        EXPJ(S2, 2, DIAG, LACC) EXPJ(S3, 3, DIAG, LACC)                 \
        PSTORE(S0, 0) PSTORE(S1, 1) PSTORE(S2, 2) PSTORE(S3, 3)         \
        __builtin_amdgcn_s_waitcnt(0xc07f); /* lgkmcnt(0) */            \
        __builtin_amdgcn_wave_barrier();                                \
        bf16x8 ap0 = *(const bf16x8*)(&P[l15 * 72 + quad * 8]);         \
        bf16x8 ap1 = *(const bf16x8*)(&P[l15 * 72 + 32 + quad * 8]);    \
        PVr(O0, vf0, vf1) PVr(O1, vf2, vf3)                             \
        PVr(O2, vf4, vf5) PVr(O3, vf6, vf7)                             \
    }

#define STORE_O(Oj, Pj, j)                                                            \
    _Pragma("unroll") for (int r_ = 0; r_ < 4; r_++) {                                \
        float v_ = Oj[r_] * lmv[r_] + Pj[r_] * lpv[r_];                               \
        y[(qrow0 + quad * 4 + r_) * NC + h * 64 + (j) * 16 + l15] = (bf16_t)v_;       \
    }

__global__ __launch_bounds__(256, 2) void k_attn9(const bf16_t* __restrict__ qkv,
                                                  const bf16_t* __restrict__ pqkv,
                                                  const bf16_t* __restrict__ vp,
                                                  const bf16_t* __restrict__ pvp,
                                                  bf16_t* __restrict__ y) {
    const int qt = (NT / 64 - 1) - blockIdx.x;  // LPT: big-qt blocks first
    const int h = blockIdx.y;
    const int b = blockIdx.z;

    __shared__ bf16_t Ks0[64 * 72], Ks1[64 * 72];
    __shared__ bf16_t Ps[4][16 * 72];

    const int tid = threadIdx.x;
    const int lane = tid & 63;
    const int wave = tid >> 6;
    const int quad = lane >> 4;
    const int l15 = lane & 15;
    const int srow = tid >> 3;       // staging row 0..31
    const int scol = (tid & 7) * 8;  // staging col offset
    const float scale = 0.125f;      // 1/sqrt(64)

    const size_t qrow0 = (size_t)b * NT + (size_t)qt * 64 + wave * 16;
    bf16_t* P = Ps[wave];

    const bf16_t* Kmain = qkv + (size_t)(b * NT) * 3072 + NC + h * 64;
    const bf16_t* Vmain = vp + (size_t)(b * NH + h) * 16 * (64 * 64);

    // Q A-fragments, loaded once
    bf16x8 aq0 = *(const bf16x8*)(qkv + (qrow0 + l15) * 3072 + h * 64 + quad * 8);
    bf16x8 aq1 = *(const bf16x8*)(qkv + (qrow0 + l15) * 3072 + h * 64 + 32 + quad * 8);

    const f32x4 fz = {0.f, 0.f, 0.f, 0.f};
    f32x4 Om0 = fz, Om1 = fz, Om2 = fz, Om3 = fz;
    f32x4 Op0 = fz, Op1 = fz, Op2 = fz, Op3 = fz;
    f32x4 Lm = fz, Lp = fz;
    uint4 rk0, rk1;
    bf16x8 vf0, vf1, vf2, vf3, vf4, vf5, vf6, vf7;

    // ---- prologue: prefix K -> Ks0; prefix V frags direct; main tile 0 K in flight ----
    LOADK(pqkv + (size_t)(b * NTP) * 3072 + NC + h * 64)
    STAGEK(Ks0)
    LOADV(pvp + (size_t)(b * NH + h) * (NTP * 64))
    LOADK(Kmain)            // main tile 0 K regs, lands during prefix PROC
    __syncthreads();        // Ks0 visible
    PROC(Ks0, qt == 0, Lp, Op0, Op1, Op2, Op3)
    LOADV(Vmain)            // V tile 0 (prefix frags consumed)
    STAGEK(Ks1)             // main tile 0 -> Ks1
    if (qt >= 1) { LOADK(Kmain + (size_t)64 * 3072) }  // main tile 1

    // ---- main causal tiles: ONE barrier per tile ----
    // main tile t lives in Ks[(t+1)&1]; STAGE at iter t writes Ks[t&1] (tile t+1)
    for (int t = 0; t <= qt; t++) {
        __syncthreads();  // Ks[(t+1)&1] visible; all reads of Ks[t&1] done
        bf16_t* KSc = (t & 1) ? Ks0 : Ks1;
        if (t < qt) {
            bf16_t* KSn = (t & 1) ? Ks1 : Ks0;
            STAGEK(KSn)  // tile t+1 (regs loaded at iter t-1 / prologue)
        }
        if (t + 1 < qt) { LOADK(Kmain + ((size_t)(t + 2) * 64) * 3072) }
        PROC(KSc, t == qt, Lm, Om0, Om1, Om2, Om3)
        if (t < qt) { LOADV(Vmain + (size_t)(t + 1) * (64 * 64)) }  // V tile t+1
    }

    // ---- single end-of-kernel row-sum reductions ----
    f32x4 lmv, lpv;
#pragma unroll
    for (int r = 0; r < 4; r++) {
        float vm = Lm[r], vpr = Lp[r];
#pragma unroll
        for (int off = 1; off < 16; off <<= 1) {
            vm += __shfl_xor(vm, off, 64);
            vpr += __shfl_xor(vpr, off, 64);
        }
        lmv[r] = 1.0f / vm;
        lpv[r] = 1.0f / vpr;
    }

    // ---- combine and store ----
    STORE_O(Om0, Op0, 0) STORE_O(Om1, Op1, 1) STORE_O(Om2, Op2, 2) STORE_O(Om3, Op3, 3)
}

// ---------------- launch ----------------
extern "C" void kernel_launch(void* const* d_in, const int* in_sizes, int n_in,
                              void* d_out, int out_size, void* d_ws, size_t ws_size,
                              hipStream_t stream) {
    (void)in_sizes; (void)n_in; (void)out_size; (void)ws_size;
    const float* x        = (const float*)d_in[0];
    const float* prefix   = (const float*)d_in[1];
    const float* w_attn   = (const float*)d_in[2];
    const float* b_attn   = (const float*)d_in[3];
    const float* w_prefix = (const float*)d_in[4];
    const float* b_prefix = (const float*)d_in[5];
    const float* w_proj   = (const float*)d_in[6];
    const float* b_proj   = (const float*)d_in[7];
    float* out = (float*)d_out;

    char* p = (char*)d_ws;
    auto carve = [&](size_t bytes) {
        char* q = p;
        p += (bytes + 255) & ~(size_t)255;
        return q;
    };
    bf16_t* xb   = (bf16_t*)carve((size_t)NB * NT * NC * 2);        // 16 MB (reused as vp)
    bf16_t* pb   = (bf16_t*)carve((size_t)NB * NTP * NC * 2);       // 1 MB  (reused as pvp)
    bf16_t* wTa  = (bf16_t*)carve((size_t)3 * NC * NC * 2);         // 6 MB
    bf16_t* wTp  = (bf16_t*)carve((size_t)3 * NC * NC * 2);         // 6 MB
    bf16_t* wTpr = (bf16_t*)carve((size_t)NC * NC * 2);             // 2 MB
    bf16_t* qkv  = (bf16_t*)carve((size_t)NB * NT * 3 * NC * 2);    // 48 MB
    bf16_t* pqkv = (bf16_t*)carve((size_t)NB * NTP * 3 * NC * 2);   // 3 MB
    bf16_t* yb   = (bf16_t*)carve((size_t)NB * NT * NC * 2);        // 16 MB

    // casts
    k_cast_bf16<<<(NB * NT * NC / 4 + 255) / 256, 256, 0, stream>>>(x, xb, NB * NT * NC / 4);
    k_cast_bf16<<<(NB * NTP * NC / 4 + 255) / 256, 256, 0, stream>>>(prefix, pb, NB * NTP * NC / 4);
    // weight transposes (to B^T bf16 layout)
    k_transpose_cast<<<dim3(3 * NC / 32, NC / 32), 256, 0, stream>>>(w_attn, wTa, NC, 3 * NC);
    k_transpose_cast<<<dim3(3 * NC / 32, NC / 32), 256, 0, stream>>>(w_prefix, wTp, NC, 3 * NC);
    k_transpose_cast<<<dim3(NC / 32, NC / 32), 256, 0, stream>>>(w_proj, wTpr, NC, NC);
    // qkv = x @ w_attn + b_attn  (bf16 out)
    k_gemm_bt<false><<<dim3(3 * NC / 128, NB * NT / 128), 256, 0, stream>>>(
        xb, wTa, b_attn, qkv, NB * NT, 3 * NC, NC);
    // pqkv = prefix @ w_prefix + b_prefix (bf16 out)
    k_gemm_bt<false><<<dim3(3 * NC / 128, NB * NTP / 128), 256, 0, stream>>>(
        pb, wTp, b_prefix, pqkv, NB * NTP, 3 * NC, NC);
    // per-head V transposes into tile-contiguous layout (xb/pb dead; reuse)
    bf16_t* vp  = xb;   // (b,h,tt,d,64)
    bf16_t* pvp = pb;   // (b,h,0,d,64)
    k_vT<<<dim3(NT / 32, ND / 32, NB * NH), 256, 0, stream>>>(qkv, vp, NT);
    k_vT<<<dim3(NTP / 32, ND / 32, NB * NH), 256, 0, stream>>>(pqkv, pvp, NTP);
    // attention
    k_attn9<<<dim3(NT / 64, NH, NB), 256, 0, stream>>>(qkv, pqkv, vp, pvp, yb);
    // out = y @ w_proj + b_proj (fp32 out)
    k_gemm_bt<true><<<dim3(NC / 128, NB * NT / 128), 256, 0, stream>>>(
        yb, wTpr, b_proj, out, NB * NT, NC, NC);
}

// Round 4
// 358.413 us; speedup vs baseline: 1.0770x; 1.0770x over previous
//
#include <hip/hip_runtime.h>
#include <hip/hip_bf16.h>
#include <cstdint>
#include <cstddef>

typedef __bf16 bf16_t;
typedef bf16_t bf16x8 __attribute__((ext_vector_type(8)));
typedef bf16_t bf16x4 __attribute__((ext_vector_type(4)));
typedef float f32x4 __attribute__((ext_vector_type(4)));

#define NB 8
#define NT 1024
#define NC 1024
#define NH 16
#define ND 64
#define NTP 64

// ---------------- transpose + cast: src (K,N) fp32 -> dst (N,K) bf16 ----------------
__global__ __launch_bounds__(256) void k_transpose_cast(const float* __restrict__ src,
                                                        bf16_t* __restrict__ dst,
                                                        int K, int N) {
    __shared__ float tile[32][33];
    int nt = blockIdx.x, kt = blockIdx.y;
    int tx = threadIdx.x & 31;
    int ty = threadIdx.x >> 5;  // 0..7
#pragma unroll
    for (int i = 0; i < 4; i++) {
        int r = ty + i * 8;
        tile[r][tx] = src[(size_t)(kt * 32 + r) * N + nt * 32 + tx];
    }
    __syncthreads();
#pragma unroll
    for (int i = 0; i < 4; i++) {
        int r = ty + i * 8;
        dst[(size_t)(nt * 32 + r) * K + kt * 32 + tx] = (bf16_t)tile[tx][r];
    }
}

// ---------------- GEMM: C(M,N) = A(M,K) @ BT(N,K)^T + bias ----------------
// 128x128 tile, BK=64, reg-staged global->LDS with padded stride 72.
// AF32: A is fp32, cast to bf16 during LDS staging (fuses the cast kernel).
// OMODE: 0 = bf16 C; 1 = f32 C; 2 = qkv mode: cols<2048 -> bf16 C (qkv buf),
//        cols>=2048 (the V third) -> stored ONLY to Vout in the transposed
//        tile-contiguous layout [((b*NH+h)*(TROWS/64)+t/64)*4096 + d*64 + t%64]
//        (fuses k_vT; qkv's V third is never written or read).
// TSH: log2(TROWS) for mode 2 (10 main, 6 prefix).
template <bool AF32, int OMODE, int TSH>
__global__ __launch_bounds__(256) void k_gemm_f(const void* __restrict__ A,
                                                const bf16_t* __restrict__ BT,
                                                const float* __restrict__ bias,
                                                void* __restrict__ Cout,
                                                bf16_t* __restrict__ Vout,
                                                int M, int N, int K) {
    __shared__ bf16_t As[128 * 72];
    __shared__ bf16_t Bs[128 * 72];
    const int tid = threadIdx.x;
    const int lane = tid & 63;
    const int wave = tid >> 6;
    const int quad = lane >> 4;
    const int l15 = lane & 15;
    const int wm = (wave >> 1) * 64;
    const int wn = (wave & 1) * 64;
    const size_t rowA0 = (size_t)blockIdx.y * 128;
    const size_t colB0 = (size_t)blockIdx.x * 128;

    const f32x4 fz = {0.f, 0.f, 0.f, 0.f};
    f32x4 acc[4][4];
#pragma unroll
    for (int i = 0; i < 4; i++)
#pragma unroll
        for (int j = 0; j < 4; j++) acc[i][j] = fz;

    for (int k0 = 0; k0 < K; k0 += 64) {
        __syncthreads();
#pragma unroll
        for (int i = 0; i < 4; i++) {
            int c = tid + i * 256;
            int r = c >> 3;
            int kc = (c & 7) * 8;
            if (AF32) {
                const float* Af = (const float*)A + (rowA0 + r) * (size_t)K + k0 + kc;
                float4 a0 = *(const float4*)Af;
                float4 a1 = *(const float4*)(Af + 4);
                bf16x8 av;
                av[0] = (bf16_t)a0.x; av[1] = (bf16_t)a0.y;
                av[2] = (bf16_t)a0.z; av[3] = (bf16_t)a0.w;
                av[4] = (bf16_t)a1.x; av[5] = (bf16_t)a1.y;
                av[6] = (bf16_t)a1.z; av[7] = (bf16_t)a1.w;
                *(bf16x8*)(&As[r * 72 + kc]) = av;
            } else {
                uint4 av = *(const uint4*)((const bf16_t*)A + (rowA0 + r) * (size_t)K + k0 + kc);
                *(uint4*)(&As[r * 72 + kc]) = av;
            }
            uint4 bv = *(const uint4*)(BT + (colB0 + r) * (size_t)K + k0 + kc);
            *(uint4*)(&Bs[r * 72 + kc]) = bv;
        }
        __syncthreads();
#pragma unroll
        for (int kk = 0; kk < 2; kk++) {
            bf16x8 af[4], bfr[4];
#pragma unroll
            for (int i = 0; i < 4; i++)
                af[i] = *(const bf16x8*)(&As[(wm + i * 16 + l15) * 72 + kk * 32 + quad * 8]);
#pragma unroll
            for (int j = 0; j < 4; j++)
                bfr[j] = *(const bf16x8*)(&Bs[(wn + j * 16 + l15) * 72 + kk * 32 + quad * 8]);
#pragma unroll
            for (int i = 0; i < 4; i++)
#pragma unroll
                for (int j = 0; j < 4; j++)
                    acc[i][j] = __builtin_amdgcn_mfma_f32_16x16x32_bf16(af[i], bfr[j], acc[i][j], 0, 0, 0);
        }
    }
    const bool vpath = (OMODE == 2) && (colB0 >= (size_t)(2 * NC));
#pragma unroll
    for (int i = 0; i < 4; i++) {
        size_t row = rowA0 + wm + i * 16 + quad * 4;
#pragma unroll
        for (int j = 0; j < 4; j++) {
            int col = (int)colB0 + wn + j * 16 + l15;
            float bv = bias[col];
            if (vpath) {
                int hh = (col - 2 * NC) >> 6;
                int dd = col & 63;
                int bb = (int)(row >> TSH);
                int tt = (int)row & ((1 << TSH) - 1);
                size_t addr = ((size_t)(bb * NH + hh) * (1 << (TSH - 6)) + (tt >> 6)) * 4096
                              + (size_t)dd * 64 + (tt & 63);
                bf16x4 vv;
#pragma unroll
                for (int r = 0; r < 4; r++) vv[r] = (bf16_t)(acc[i][j][r] + bv);
                *(bf16x4*)(Vout + addr) = vv;
            } else {
#pragma unroll
                for (int r = 0; r < 4; r++) {
                    float v = acc[i][j][r] + bv;
                    if (OMODE == 1)
                        ((float*)Cout)[(row + r) * (size_t)N + col] = v;
                    else
                        ((bf16_t*)Cout)[(row + r) * (size_t)N + col] = (bf16_t)v;
                }
            }
        }
    }
}

// ---------------- fused dual-softmax causal attention (R2 v8, 82 us) ----------------
// Double-buffered K/V LDS -> ONE __syncthreads per tile; staging ds_writes of
// tile t+1 overlap PROC of tile t; global loads issued ~1.5 tiles ahead.
// (R3's V-direct-from-global variant regressed 82->150 us: 4x intra-block V
//  re-gather from L2 + uncovered L2 latency. LDS V-stage amortizes across waves.)

#define LOADREGS(KB, VB)                                                  \
    rk0 = *(const uint4*)((KB) + (size_t)srow * 3072 + scol);             \
    rk1 = *(const uint4*)((KB) + (size_t)(srow + 32) * 3072 + scol);      \
    rv0 = *(const uint4*)((VB) + (size_t)tid * 8);                        \
    rv1 = *(const uint4*)((VB) + (size_t)(tid + 256) * 8);

#define STAGE(KS, VS)                                     \
    *(uint4*)(&(KS)[srow * 72 + scol]) = rk0;             \
    *(uint4*)(&(KS)[(srow + 32) * 72 + scol]) = rk1;      \
    *(uint4*)(&(VS)[srow * 72 + scol]) = rv0;             \
    *(uint4*)(&(VS)[(srow + 32) * 72 + scol]) = rv1;

#define QK(KS, Sj, j)                                                                  \
    Sj = __builtin_amdgcn_mfma_f32_16x16x32_bf16(                                      \
        aq0, *(const bf16x8*)(&(KS)[((j) * 16 + l15) * 72 + quad * 8]), Sj, 0, 0, 0);  \
    Sj = __builtin_amdgcn_mfma_f32_16x16x32_bf16(                                      \
        aq1, *(const bf16x8*)(&(KS)[((j) * 16 + l15) * 72 + 32 + quad * 8]), Sj, 0, 0, 0);

#define EXPJ(Sj, j, DIAG, LACC)                                         \
    {                                                                   \
        const int n_ = (j) * 16 + l15;                                  \
        _Pragma("unroll") for (int r_ = 0; r_ < 4; r_++) {              \
            float p_ = __expf(Sj[r_] * scale);                          \
            if ((DIAG) && n_ > wave * 16 + quad * 4 + r_) p_ = 0.f;     \
            Sj[r_] = p_;                                                \
            LACC[r_] += p_;                                             \
        }                                                               \
    }

#define PSTORE(Sj, j)                                                   \
    _Pragma("unroll") for (int r_ = 0; r_ < 4; r_++)                    \
        P[(quad * 4 + r_) * 72 + (j) * 16 + l15] = (bf16_t)Sj[r_];

#define PV(VS, Oj, j)                                                                  \
    Oj = __builtin_amdgcn_mfma_f32_16x16x32_bf16(                                      \
        ap0, *(const bf16x8*)(&(VS)[((j) * 16 + l15) * 72 + quad * 8]), Oj, 0, 0, 0);  \
    Oj = __builtin_amdgcn_mfma_f32_16x16x32_bf16(                                      \
        ap1, *(const bf16x8*)(&(VS)[((j) * 16 + l15) * 72 + 32 + quad * 8]), Oj, 0, 0, 0);

#define PROC(KS, VS, DIAG, LACC, O0, O1, O2, O3)                        \
    {                                                                   \
        f32x4 S0 = fz, S1 = fz, S2 = fz, S3 = fz;                       \
        QK(KS, S0, 0) QK(KS, S1, 1) QK(KS, S2, 2) QK(KS, S3, 3)         \
        EXPJ(S0, 0, DIAG, LACC) EXPJ(S1, 1, DIAG, LACC)                 \
        EXPJ(S2, 2, DIAG, LACC) EXPJ(S3, 3, DIAG, LACC)                 \
        PSTORE(S0, 0) PSTORE(S1, 1) PSTORE(S2, 2) PSTORE(S3, 3)         \
        __builtin_amdgcn_s_waitcnt(0xc07f); /* lgkmcnt(0) */            \
        __builtin_amdgcn_wave_barrier();                                \
        bf16x8 ap0 = *(const bf16x8*)(&P[l15 * 72 + quad * 8]);         \
        bf16x8 ap1 = *(const bf16x8*)(&P[l15 * 72 + 32 + quad * 8]);    \
        PV(VS, O0, 0) PV(VS, O1, 1) PV(VS, O2, 2) PV(VS, O3, 3)         \
    }

#define STORE_O(Oj, Pj, j)                                                            \
    _Pragma("unroll") for (int r_ = 0; r_ < 4; r_++) {                                \
        float v_ = Oj[r_] * lmv[r_] + Pj[r_] * lpv[r_];                               \
        y[(qrow0 + quad * 4 + r_) * NC + h * 64 + (j) * 16 + l15] = (bf16_t)v_;       \
    }

__global__ __launch_bounds__(256, 2) void k_attn8(const bf16_t* __restrict__ qkv,
                                                  const bf16_t* __restrict__ pqkv,
                                                  const bf16_t* __restrict__ vp,
                                                  const bf16_t* __restrict__ pvp,
                                                  bf16_t* __restrict__ y) {
    const int qt = (NT / 64 - 1) - blockIdx.x;  // LPT: big-qt blocks first
    const int h = blockIdx.y;
    const int b = blockIdx.z;

    __shared__ bf16_t Ks0[64 * 72], Ks1[64 * 72];
    __shared__ bf16_t Vs0[64 * 72], Vs1[64 * 72];
    __shared__ bf16_t Ps[4][16 * 72];

    const int tid = threadIdx.x;
    const int lane = tid & 63;
    const int wave = tid >> 6;
    const int quad = lane >> 4;
    const int l15 = lane & 15;
    const int srow = tid >> 3;       // staging row 0..31
    const int scol = (tid & 7) * 8;  // staging col offset
    const float scale = 0.125f;      // 1/sqrt(64)

    const size_t qrow0 = (size_t)b * NT + (size_t)qt * 64 + wave * 16;
    bf16_t* P = Ps[wave];

    const bf16_t* Kmain = qkv + (size_t)(b * NT) * 3072 + NC + h * 64;
    const bf16_t* Vmain = vp + (size_t)(b * NH + h) * 16 * (64 * 64);

    // Q A-fragments, loaded once
    bf16x8 aq0 = *(const bf16x8*)(qkv + (qrow0 + l15) * 3072 + h * 64 + quad * 8);
    bf16x8 aq1 = *(const bf16x8*)(qkv + (qrow0 + l15) * 3072 + h * 64 + 32 + quad * 8);

    const f32x4 fz = {0.f, 0.f, 0.f, 0.f};
    f32x4 Om0 = fz, Om1 = fz, Om2 = fz, Om3 = fz;
    f32x4 Op0 = fz, Op1 = fz, Op2 = fz, Op3 = fz;
    f32x4 Lm = fz, Lp = fz;
    uint4 rk0, rk1, rv0, rv1;

    // ---- prologue: prefix tile -> buf0; main tile 0 loads in flight ----
    LOADREGS(pqkv + (size_t)(b * NTP) * 3072 + NC + h * 64,
             pvp + (size_t)(b * NH + h) * (NTP * 64))
    STAGE(Ks0, Vs0)
    LOADREGS(Kmain, Vmain)  // main tile 0, lands during prefix PROC
    __syncthreads();        // buf0 visible
    PROC(Ks0, Vs0, qt == 0, Lp, Op0, Op1, Op2, Op3)
    STAGE(Ks1, Vs1)         // main tile 0 -> buf1 (nobody read buf1 yet)
    if (qt >= 1) { LOADREGS(Kmain + (size_t)64 * 3072, Vmain + 64 * 64) }  // main tile 1

    // ---- main causal tiles: ONE barrier per tile ----
    // main tile t lives in buf[(t+1)&1]; STAGE at iter t writes buf[t&1] (tile t+1)
    for (int t = 0; t <= qt; t++) {
        __syncthreads();  // buf[(t+1)&1] visible; all reads of buf[t&1] done
        bf16_t* KSc = (t & 1) ? Ks0 : Ks1;
        bf16_t* VSc = (t & 1) ? Vs0 : Vs1;
        if (t < qt) {
            bf16_t* KSn = (t & 1) ? Ks1 : Ks0;
            bf16_t* VSn = (t & 1) ? Vs1 : Vs0;
            STAGE(KSn, VSn)  // tile t+1 (regs loaded at iter t-1 / prologue)
        }
        if (t + 1 < qt) {
            LOADREGS(Kmain + ((size_t)(t + 2) * 64) * 3072, Vmain + (size_t)(t + 2) * (64 * 64))
        }
        PROC(KSc, VSc, t == qt, Lm, Om0, Om1, Om2, Om3)
    }

    // ---- single end-of-kernel row-sum reductions ----
    f32x4 lmv, lpv;
#pragma unroll
    for (int r = 0; r < 4; r++) {
        float vm = Lm[r], vpr = Lp[r];
#pragma unroll
        for (int off = 1; off < 16; off <<= 1) {
            vm += __shfl_xor(vm, off, 64);
            vpr += __shfl_xor(vpr, off, 64);
        }
        lmv[r] = 1.0f / vm;
        lpv[r] = 1.0f / vpr;
    }

    // ---- combine and store ----
    STORE_O(Om0, Op0, 0) STORE_O(Om1, Op1, 1) STORE_O(Om2, Op2, 2) STORE_O(Om3, Op3, 3)
}

// ---------------- launch ----------------
extern "C" void kernel_launch(void* const* d_in, const int* in_sizes, int n_in,
                              void* d_out, int out_size, void* d_ws, size_t ws_size,
                              hipStream_t stream) {
    (void)in_sizes; (void)n_in; (void)out_size; (void)ws_size;
    const float* x        = (const float*)d_in[0];
    const float* prefix   = (const float*)d_in[1];
    const float* w_attn   = (const float*)d_in[2];
    const float* b_attn   = (const float*)d_in[3];
    const float* w_prefix = (const float*)d_in[4];
    const float* b_prefix = (const float*)d_in[5];
    const float* w_proj   = (const float*)d_in[6];
    const float* b_proj   = (const float*)d_in[7];
    float* out = (float*)d_out;

    char* p = (char*)d_ws;
    auto carve = [&](size_t bytes) {
        char* q = p;
        p += (bytes + 255) & ~(size_t)255;
        return q;
    };
    bf16_t* vp   = (bf16_t*)carve((size_t)NB * NT * NC * 2);        // 16 MB (V transposed tiles)
    bf16_t* pvp  = (bf16_t*)carve((size_t)NB * NTP * NC * 2);       // 1 MB
    bf16_t* wTa  = (bf16_t*)carve((size_t)3 * NC * NC * 2);         // 6 MB
    bf16_t* wTp  = (bf16_t*)carve((size_t)3 * NC * NC * 2);         // 6 MB
    bf16_t* wTpr = (bf16_t*)carve((size_t)NC * NC * 2);             // 2 MB
    bf16_t* qkv  = (bf16_t*)carve((size_t)NB * NT * 3 * NC * 2);    // 48 MB (V third unused)
    bf16_t* pqkv = (bf16_t*)carve((size_t)NB * NTP * 3 * NC * 2);   // 3 MB (V third unused)
    bf16_t* yb   = (bf16_t*)carve((size_t)NB * NT * NC * 2);        // 16 MB

    // weight transposes (to B^T bf16 layout)
    k_transpose_cast<<<dim3(3 * NC / 32, NC / 32), 256, 0, stream>>>(w_attn, wTa, NC, 3 * NC);
    k_transpose_cast<<<dim3(3 * NC / 32, NC / 32), 256, 0, stream>>>(w_prefix, wTp, NC, 3 * NC);
    k_transpose_cast<<<dim3(NC / 32, NC / 32), 256, 0, stream>>>(w_proj, wTpr, NC, NC);
    // qkv = x @ w_attn + b_attn  (fused fp32-A cast; V third -> vp transposed)
    k_gemm_f<true, 2, 10><<<dim3(3 * NC / 128, NB * NT / 128), 256, 0, stream>>>(
        x, wTa, b_attn, qkv, vp, NB * NT, 3 * NC, NC);
    // pqkv = prefix @ w_prefix + b_prefix (fused cast; V third -> pvp transposed)
    k_gemm_f<true, 2, 6><<<dim3(3 * NC / 128, NB * NTP / 128), 256, 0, stream>>>(
        prefix, wTp, b_prefix, pqkv, pvp, NB * NTP, 3 * NC, NC);
    // attention
    k_attn8<<<dim3(NT / 64, NH, NB), 256, 0, stream>>>(qkv, pqkv, vp, pvp, yb);
    // out = y @ w_proj + b_proj (fp32 out)
    k_gemm_f<false, 1, 6><<<dim3(NC / 128, NB * NT / 128), 256, 0, stream>>>(
        yb, wTpr, b_proj, out, nullptr, NB * NT, NC, NC);
}

// Round 5
// 310.909 us; speedup vs baseline: 1.2416x; 1.1528x over previous
//
#include <hip/hip_runtime.h>
#include <hip/hip_bf16.h>
#include <cstdint>
#include <cstddef>

typedef __bf16 bf16_t;
typedef bf16_t bf16x8 __attribute__((ext_vector_type(8)));
typedef bf16_t bf16x4 __attribute__((ext_vector_type(4)));
typedef float f32x4 __attribute__((ext_vector_type(4)));

#define NB 8
#define NT 1024
#define NC 1024
#define NH 16
#define ND 64
#define NTP 64

// ---------------- fused cast fp32 -> bf16 for x and prefix (one launch) ----------------
__global__ __launch_bounds__(256) void k_cast2(const float* __restrict__ a, bf16_t* __restrict__ da,
                                               int n4a,
                                               const float* __restrict__ b2, bf16_t* __restrict__ db,
                                               int n4b) {
    int i = blockIdx.x * 256 + threadIdx.x;
    if (i < n4a) {
        float4 f = ((const float4*)a)[i];
        bf16x4 o;
        o[0] = (bf16_t)f.x; o[1] = (bf16_t)f.y; o[2] = (bf16_t)f.z; o[3] = (bf16_t)f.w;
        ((bf16x4*)da)[i] = o;
    } else {
        int j = i - n4a;
        if (j < n4b) {
            float4 f = ((const float4*)b2)[j];
            bf16x4 o;
            o[0] = (bf16_t)f.x; o[1] = (bf16_t)f.y; o[2] = (bf16_t)f.z; o[3] = (bf16_t)f.w;
            ((bf16x4*)db)[j] = o;
        }
    }
}

// ------- all 3 weight transposes (K,N) fp32 -> (N,K) bf16 in ONE launch -------
__global__ __launch_bounds__(256) void k_transpose3(const float* __restrict__ s0, bf16_t* __restrict__ d0,
                                                    const float* __restrict__ s1, bf16_t* __restrict__ d1,
                                                    const float* __restrict__ s2, bf16_t* __restrict__ d2) {
    __shared__ float tile[32][33];
    const int z = blockIdx.z;
    const float* src = (z == 0) ? s0 : (z == 1) ? s1 : s2;
    bf16_t* dst = (z == 0) ? d0 : (z == 1) ? d1 : d2;
    const int N = (z == 2) ? NC : 3 * NC;
    const int K = NC;
    if (z == 2 && blockIdx.x >= 32) return;
    int nt = blockIdx.x, kt = blockIdx.y;
    int tx = threadIdx.x & 31;
    int ty = threadIdx.x >> 5;  // 0..7
#pragma unroll
    for (int i = 0; i < 4; i++) {
        int r = ty + i * 8;
        tile[r][tx] = src[(size_t)(kt * 32 + r) * N + nt * 32 + tx];
    }
    __syncthreads();
#pragma unroll
    for (int i = 0; i < 4; i++) {
        int r = ty + i * 8;
        dst[(size_t)(nt * 32 + r) * K + kt * 32 + tx] = (bf16_t)tile[tx][r];
    }
}

// ---------------- GEMM: C(M,N) = A(M,K) @ BT(N,K)^T + bias ----------------
// 128x128 tile, BK=64, reg-staged global->LDS with padded stride 72 (R2 path, 84 us).
// OMODE 1: fp32 C out.
// OMODE 2: qkv mode. cols<2048 -> bf16 C rows (Q,K thirds). cols>=2048 (V third)
//   -> written into C's OWN V-third region under a bijective tile remap (fuses k_vT):
//   logical flat v-index f = tile*4096 + d*64 + t%64, tile = (bb*NH+hh)*(2^(TSH-6)) + t/64;
//   physical: row = f>>10, col = 2048 + (f&1023). Attention reads V through the
//   same mapping. (fp32-A fusion from R4 REVERTED: +67 MB HBM fetch, +38 us.)
template <int OMODE, int TSH>
__global__ __launch_bounds__(256) void k_gemm_f(const bf16_t* __restrict__ A,
                                                const bf16_t* __restrict__ BT,
                                                const float* __restrict__ bias,
                                                void* __restrict__ Cout,
                                                int M, int N, int K) {
    __shared__ bf16_t As[128 * 72];
    __shared__ bf16_t Bs[128 * 72];
    const int tid = threadIdx.x;
    const int lane = tid & 63;
    const int wave = tid >> 6;
    const int quad = lane >> 4;
    const int l15 = lane & 15;
    const int wm = (wave >> 1) * 64;
    const int wn = (wave & 1) * 64;
    const size_t rowA0 = (size_t)blockIdx.y * 128;
    const size_t colB0 = (size_t)blockIdx.x * 128;

    const f32x4 fz = {0.f, 0.f, 0.f, 0.f};
    f32x4 acc[4][4];
#pragma unroll
    for (int i = 0; i < 4; i++)
#pragma unroll
        for (int j = 0; j < 4; j++) acc[i][j] = fz;

    for (int k0 = 0; k0 < K; k0 += 64) {
        __syncthreads();
#pragma unroll
        for (int i = 0; i < 4; i++) {
            int c = tid + i * 256;
            int r = c >> 3;
            int kc = (c & 7) * 8;
            uint4 av = *(const uint4*)(A + (rowA0 + r) * (size_t)K + k0 + kc);
            *(uint4*)(&As[r * 72 + kc]) = av;
            uint4 bv = *(const uint4*)(BT + (colB0 + r) * (size_t)K + k0 + kc);
            *(uint4*)(&Bs[r * 72 + kc]) = bv;
        }
        __syncthreads();
#pragma unroll
        for (int kk = 0; kk < 2; kk++) {
            bf16x8 af[4], bfr[4];
#pragma unroll
            for (int i = 0; i < 4; i++)
                af[i] = *(const bf16x8*)(&As[(wm + i * 16 + l15) * 72 + kk * 32 + quad * 8]);
#pragma unroll
            for (int j = 0; j < 4; j++)
                bfr[j] = *(const bf16x8*)(&Bs[(wn + j * 16 + l15) * 72 + kk * 32 + quad * 8]);
#pragma unroll
            for (int i = 0; i < 4; i++)
#pragma unroll
                for (int j = 0; j < 4; j++)
                    acc[i][j] = __builtin_amdgcn_mfma_f32_16x16x32_bf16(af[i], bfr[j], acc[i][j], 0, 0, 0);
        }
    }
    const bool vpath = (OMODE == 2) && (colB0 >= (size_t)(2 * NC));
#pragma unroll
    for (int i = 0; i < 4; i++) {
        size_t row = rowA0 + wm + i * 16 + quad * 4;
#pragma unroll
        for (int j = 0; j < 4; j++) {
            int col = (int)colB0 + wn + j * 16 + l15;
            float bv = bias[col];
            if (vpath) {
                int hh = (col - 2 * NC) >> 6;
                int dd = col & 63;
                int bb = (int)(row >> TSH);
                int tt = (int)row & ((1 << TSH) - 1);
                int tileBase = (bb * NH + hh) * (1 << (TSH - 6)) + (tt >> 6);
                size_t chunkrow = (size_t)tileBase * 4 + (dd >> 4);
                size_t addr = chunkrow * (size_t)N + 2 * NC + (dd & 15) * 64 + (tt & 63);
                bf16x4 vv;
#pragma unroll
                for (int r = 0; r < 4; r++) vv[r] = (bf16_t)(acc[i][j][r] + bv);
                *(bf16x4*)((bf16_t*)Cout + addr) = vv;
            } else {
#pragma unroll
                for (int r = 0; r < 4; r++) {
                    float v = acc[i][j][r] + bv;
                    if (OMODE == 1)
                        ((float*)Cout)[(row + r) * (size_t)N + col] = v;
                    else
                        ((bf16_t*)Cout)[(row + r) * (size_t)N + col] = (bf16_t)v;
                }
            }
        }
    }
}

// ---------------- fused dual-softmax causal attention (R2 v8 + setprio) --------------
// Double-buffered K/V LDS -> ONE __syncthreads per tile; staging ds_writes of
// tile t+1 overlap PROC of tile t; global loads issued ~1.5 tiles ahead.
// V is read from qkv/pqkv's V-third via the bijective tile remap (see k_gemm_f):
// flat offset f within a 4096-elem V tile lives at chunkbase + (f>>10)*3072 + (f&1023).

#define LOADREGS(KB, VCB)                                                            \
    rk0 = *(const uint4*)((KB) + (size_t)srow * 3072 + scol);                        \
    rk1 = *(const uint4*)((KB) + (size_t)(srow + 32) * 3072 + scol);                 \
    rv0 = *(const uint4*)((VCB) + (size_t)(tid >> 7) * 3072 + (tid & 127) * 8);      \
    rv1 = *(const uint4*)((VCB) + (size_t)((tid >> 7) + 2) * 3072 + (tid & 127) * 8);

#define STAGE(KS, VS)                                     \
    *(uint4*)(&(KS)[srow * 72 + scol]) = rk0;             \
    *(uint4*)(&(KS)[(srow + 32) * 72 + scol]) = rk1;      \
    *(uint4*)(&(VS)[srow * 72 + scol]) = rv0;             \
    *(uint4*)(&(VS)[(srow + 32) * 72 + scol]) = rv1;

#define QK(KS, Sj, j)                                                                  \
    Sj = __builtin_amdgcn_mfma_f32_16x16x32_bf16(                                      \
        aq0, *(const bf16x8*)(&(KS)[((j) * 16 + l15) * 72 + quad * 8]), Sj, 0, 0, 0);  \
    Sj = __builtin_amdgcn_mfma_f32_16x16x32_bf16(                                      \
        aq1, *(const bf16x8*)(&(KS)[((j) * 16 + l15) * 72 + 32 + quad * 8]), Sj, 0, 0, 0);

#define EXPJ(Sj, j, DIAG, LACC)                                         \
    {                                                                   \
        const int n_ = (j) * 16 + l15;                                  \
        _Pragma("unroll") for (int r_ = 0; r_ < 4; r_++) {              \
            float p_ = __expf(Sj[r_] * scale);                          \
            if ((DIAG) && n_ > wave * 16 + quad * 4 + r_) p_ = 0.f;     \
            Sj[r_] = p_;                                                \
            LACC[r_] += p_;                                             \
        }                                                               \
    }

#define PSTORE(Sj, j)                                                   \
    _Pragma("unroll") for (int r_ = 0; r_ < 4; r_++)                    \
        P[(quad * 4 + r_) * 72 + (j) * 16 + l15] = (bf16_t)Sj[r_];

#define PV(VS, Oj, j)                                                                  \
    Oj = __builtin_amdgcn_mfma_f32_16x16x32_bf16(                                      \
        ap0, *(const bf16x8*)(&(VS)[((j) * 16 + l15) * 72 + quad * 8]), Oj, 0, 0, 0);  \
    Oj = __builtin_amdgcn_mfma_f32_16x16x32_bf16(                                      \
        ap1, *(const bf16x8*)(&(VS)[((j) * 16 + l15) * 72 + 32 + quad * 8]), Oj, 0, 0, 0);

#define PROC(KS, VS, DIAG, LACC, O0, O1, O2, O3)                        \
    {                                                                   \
        f32x4 S0 = fz, S1 = fz, S2 = fz, S3 = fz;                       \
        __builtin_amdgcn_s_setprio(1);                                  \
        QK(KS, S0, 0) QK(KS, S1, 1) QK(KS, S2, 2) QK(KS, S3, 3)         \
        __builtin_amdgcn_s_setprio(0);                                  \
        EXPJ(S0, 0, DIAG, LACC) EXPJ(S1, 1, DIAG, LACC)                 \
        EXPJ(S2, 2, DIAG, LACC) EXPJ(S3, 3, DIAG, LACC)                 \
        PSTORE(S0, 0) PSTORE(S1, 1) PSTORE(S2, 2) PSTORE(S3, 3)         \
        __builtin_amdgcn_s_waitcnt(0xc07f); /* lgkmcnt(0) */            \
        __builtin_amdgcn_wave_barrier();                                \
        bf16x8 ap0 = *(const bf16x8*)(&P[l15 * 72 + quad * 8]);         \
        bf16x8 ap1 = *(const bf16x8*)(&P[l15 * 72 + 32 + quad * 8]);    \
        __builtin_amdgcn_s_setprio(1);                                  \
        PV(VS, O0, 0) PV(VS, O1, 1) PV(VS, O2, 2) PV(VS, O3, 3)         \
        __builtin_amdgcn_s_setprio(0);                                  \
    }

#define STORE_O(Oj, Pj, j)                                                            \
    _Pragma("unroll") for (int r_ = 0; r_ < 4; r_++) {                                \
        float v_ = Oj[r_] * lmv[r_] + Pj[r_] * lpv[r_];                               \
        y[(qrow0 + quad * 4 + r_) * NC + h * 64 + (j) * 16 + l15] = (bf16_t)v_;       \
    }

__global__ __launch_bounds__(256, 2) void k_attn10(const bf16_t* __restrict__ qkv,
                                                   const bf16_t* __restrict__ pqkv,
                                                   bf16_t* __restrict__ y) {
    const int qt = (NT / 64 - 1) - blockIdx.x;  // LPT: big-qt blocks first
    const int h = blockIdx.y;
    const int b = blockIdx.z;

    __shared__ bf16_t Ks0[64 * 72], Ks1[64 * 72];
    __shared__ bf16_t Vs0[64 * 72], Vs1[64 * 72];
    __shared__ bf16_t Ps[4][16 * 72];

    const int tid = threadIdx.x;
    const int lane = tid & 63;
    const int wave = tid >> 6;
    const int quad = lane >> 4;
    const int l15 = lane & 15;
    const int srow = tid >> 3;       // staging row 0..31
    const int scol = (tid & 7) * 8;  // staging col offset
    const float scale = 0.125f;      // 1/sqrt(64)

    const size_t qrow0 = (size_t)b * NT + (size_t)qt * 64 + wave * 16;
    bf16_t* P = Ps[wave];

    const bf16_t* Kmain = qkv + (size_t)(b * NT) * 3072 + NC + h * 64;
    // V chunk-bases inside the qkv/pqkv V-thirds (tile t: +t*4*3072)
    const bf16_t* Vmain = qkv + (size_t)(b * NH + h) * 16 * 4 * 3072 + 2 * NC;
    const bf16_t* Vpre  = pqkv + (size_t)(b * NH + h) * 4 * 3072 + 2 * NC;

    // Q A-fragments, loaded once
    bf16x8 aq0 = *(const bf16x8*)(qkv + (qrow0 + l15) * 3072 + h * 64 + quad * 8);
    bf16x8 aq1 = *(const bf16x8*)(qkv + (qrow0 + l15) * 3072 + h * 64 + 32 + quad * 8);

    const f32x4 fz = {0.f, 0.f, 0.f, 0.f};
    f32x4 Om0 = fz, Om1 = fz, Om2 = fz, Om3 = fz;
    f32x4 Op0 = fz, Op1 = fz, Op2 = fz, Op3 = fz;
    f32x4 Lm = fz, Lp = fz;
    uint4 rk0, rk1, rv0, rv1;

    // ---- prologue: prefix tile -> buf0; main tile 0 loads in flight ----
    LOADREGS(pqkv + (size_t)(b * NTP) * 3072 + NC + h * 64, Vpre)
    STAGE(Ks0, Vs0)
    LOADREGS(Kmain, Vmain)  // main tile 0, lands during prefix PROC
    __syncthreads();        // buf0 visible
    PROC(Ks0, Vs0, qt == 0, Lp, Op0, Op1, Op2, Op3)
    STAGE(Ks1, Vs1)         // main tile 0 -> buf1 (nobody read buf1 yet)
    if (qt >= 1) { LOADREGS(Kmain + (size_t)64 * 3072, Vmain + 4 * 3072) }  // main tile 1

    // ---- main causal tiles: ONE barrier per tile ----
    // main tile t lives in buf[(t+1)&1]; STAGE at iter t writes buf[t&1] (tile t+1)
    for (int t = 0; t <= qt; t++) {
        __syncthreads();  // buf[(t+1)&1] visible; all reads of buf[t&1] done
        bf16_t* KSc = (t & 1) ? Ks0 : Ks1;
        bf16_t* VSc = (t & 1) ? Vs0 : Vs1;
        if (t < qt) {
            bf16_t* KSn = (t & 1) ? Ks1 : Ks0;
            bf16_t* VSn = (t & 1) ? Vs1 : Vs0;
            STAGE(KSn, VSn)  // tile t+1 (regs loaded at iter t-1 / prologue)
        }
        if (t + 1 < qt) {
            LOADREGS(Kmain + ((size_t)(t + 2) * 64) * 3072, Vmain + (size_t)(t + 2) * 4 * 3072)
        }
        PROC(KSc, VSc, t == qt, Lm, Om0, Om1, Om2, Om3)
    }

    // ---- single end-of-kernel row-sum reductions ----
    f32x4 lmv, lpv;
#pragma unroll
    for (int r = 0; r < 4; r++) {
        float vm = Lm[r], vpr = Lp[r];
#pragma unroll
        for (int off = 1; off < 16; off <<= 1) {
            vm += __shfl_xor(vm, off, 64);
            vpr += __shfl_xor(vpr, off, 64);
        }
        lmv[r] = 1.0f / vm;
        lpv[r] = 1.0f / vpr;
    }

    // ---- combine and store ----
    STORE_O(Om0, Op0, 0) STORE_O(Om1, Op1, 1) STORE_O(Om2, Op2, 2) STORE_O(Om3, Op3, 3)
}

// ---------------- launch ----------------
extern "C" void kernel_launch(void* const* d_in, const int* in_sizes, int n_in,
                              void* d_out, int out_size, void* d_ws, size_t ws_size,
                              hipStream_t stream) {
    (void)in_sizes; (void)n_in; (void)out_size; (void)ws_size;
    const float* x        = (const float*)d_in[0];
    const float* prefix   = (const float*)d_in[1];
    const float* w_attn   = (const float*)d_in[2];
    const float* b_attn   = (const float*)d_in[3];
    const float* w_prefix = (const float*)d_in[4];
    const float* b_prefix = (const float*)d_in[5];
    const float* w_proj   = (const float*)d_in[6];
    const float* b_proj   = (const float*)d_in[7];
    float* out = (float*)d_out;

    char* p = (char*)d_ws;
    auto carve = [&](size_t bytes) {
        char* q = p;
        p += (bytes + 255) & ~(size_t)255;
        return q;
    };
    bf16_t* xb   = (bf16_t*)carve((size_t)NB * NT * NC * 2);        // 16 MB
    bf16_t* pb   = (bf16_t*)carve((size_t)NB * NTP * NC * 2);       // 1 MB
    bf16_t* wTa  = (bf16_t*)carve((size_t)3 * NC * NC * 2);         // 6 MB
    bf16_t* wTp  = (bf16_t*)carve((size_t)3 * NC * NC * 2);         // 6 MB
    bf16_t* wTpr = (bf16_t*)carve((size_t)NC * NC * 2);             // 2 MB
    bf16_t* qkv  = (bf16_t*)carve((size_t)NB * NT * 3 * NC * 2);    // 48 MB (V third = tiled V)
    bf16_t* pqkv = (bf16_t*)carve((size_t)NB * NTP * 3 * NC * 2);   // 3 MB (V third = tiled V)
    bf16_t* yb   = (bf16_t*)carve((size_t)NB * NT * NC * 2);        // 16 MB

    const int n4a = NB * NT * NC / 4, n4b = NB * NTP * NC / 4;
    // fused casts (1 launch)
    k_cast2<<<(n4a + n4b + 255) / 256, 256, 0, stream>>>(x, xb, n4a, prefix, pb, n4b);
    // all weight transposes (1 launch)
    k_transpose3<<<dim3(3 * NC / 32, NC / 32, 3), 256, 0, stream>>>(w_attn, wTa, w_prefix, wTp,
                                                                    w_proj, wTpr);
    // qkv = x @ w_attn + b_attn  (V third stored in transposed tile layout in-place)
    k_gemm_f<2, 10><<<dim3(3 * NC / 128, NB * NT / 128), 256, 0, stream>>>(
        xb, wTa, b_attn, qkv, NB * NT, 3 * NC, NC);
    // pqkv = prefix @ w_prefix + b_prefix
    k_gemm_f<2, 6><<<dim3(3 * NC / 128, NB * NTP / 128), 256, 0, stream>>>(
        pb, wTp, b_prefix, pqkv, NB * NTP, 3 * NC, NC);
    // attention
    k_attn10<<<dim3(NT / 64, NH, NB), 256, 0, stream>>>(qkv, pqkv, yb);
    // out = y @ w_proj + b_proj (fp32 out)
    k_gemm_f<1, 6><<<dim3(NC / 128, NB * NT / 128), 256, 0, stream>>>(
        yb, wTpr, b_proj, out, NB * NT, NC, NC);
}

// Round 6
// 307.891 us; speedup vs baseline: 1.2538x; 1.0098x over previous
//
#include <hip/hip_runtime.h>
#include <hip/hip_bf16.h>
#include <cstdint>
#include <cstddef>

typedef __bf16 bf16_t;
typedef bf16_t bf16x8 __attribute__((ext_vector_type(8)));
typedef bf16_t bf16x4 __attribute__((ext_vector_type(4)));
typedef float f32x4 __attribute__((ext_vector_type(4)));

#define NB 8
#define NT 1024
#define NC 1024
#define NH 16
#define ND 64
#define NTP 64

// ---------------- fused cast fp32 -> bf16 for x and prefix (one launch) ----------------
__global__ __launch_bounds__(256) void k_cast2(const float* __restrict__ a, bf16_t* __restrict__ da,
                                               int n4a,
                                               const float* __restrict__ b2, bf16_t* __restrict__ db,
                                               int n4b) {
    int i = blockIdx.x * 256 + threadIdx.x;
    if (i < n4a) {
        float4 f = ((const float4*)a)[i];
        bf16x4 o;
        o[0] = (bf16_t)f.x; o[1] = (bf16_t)f.y; o[2] = (bf16_t)f.z; o[3] = (bf16_t)f.w;
        ((bf16x4*)da)[i] = o;
    } else {
        int j = i - n4a;
        if (j < n4b) {
            float4 f = ((const float4*)b2)[j];
            bf16x4 o;
            o[0] = (bf16_t)f.x; o[1] = (bf16_t)f.y; o[2] = (bf16_t)f.z; o[3] = (bf16_t)f.w;
            ((bf16x4*)db)[j] = o;
        }
    }
}

// ------- all 3 weight transposes (K,N) fp32 -> (N,K) bf16 in ONE launch -------
__global__ __launch_bounds__(256) void k_transpose3(const float* __restrict__ s0, bf16_t* __restrict__ d0,
                                                    const float* __restrict__ s1, bf16_t* __restrict__ d1,
                                                    const float* __restrict__ s2, bf16_t* __restrict__ d2) {
    __shared__ float tile[32][33];
    const int z = blockIdx.z;
    const float* src = (z == 0) ? s0 : (z == 1) ? s1 : s2;
    bf16_t* dst = (z == 0) ? d0 : (z == 1) ? d1 : d2;
    const int N = (z == 2) ? NC : 3 * NC;
    const int K = NC;
    if (z == 2 && blockIdx.x >= 32) return;
    int nt = blockIdx.x, kt = blockIdx.y;
    int tx = threadIdx.x & 31;
    int ty = threadIdx.x >> 5;  // 0..7
#pragma unroll
    for (int i = 0; i < 4; i++) {
        int r = ty + i * 8;
        tile[r][tx] = src[(size_t)(kt * 32 + r) * N + nt * 32 + tx];
    }
    __syncthreads();
#pragma unroll
    for (int i = 0; i < 4; i++) {
        int r = ty + i * 8;
        dst[(size_t)(nt * 32 + r) * K + kt * 32 + tx] = (bf16_t)tile[tx][r];
    }
}

// ---------------- GEMM: C(M,N) = A(M,K) @ BT(N,K)^T + bias ----------------
// 128x128 tile, BK=64, reg-staged global->LDS with padded stride 72 (R2 path, ~85 us).
// OMODE 1: fp32 C out.
// OMODE 2: qkv mode. cols<2048 -> bf16 C rows (Q,K thirds). cols>=2048 (V third)
//   -> written into C's OWN V-third region under a bijective tile remap (fuses k_vT):
//   logical flat v-index f = tile*4096 + d*64 + t%64, tile = (bb*NH+hh)*(2^(TSH-6)) + t/64;
//   physical: row = f>>10, col = 2048 + (f&1023). Attention reads V via the same map.
template <int OMODE, int TSH>
__global__ __launch_bounds__(256) void k_gemm_f(const bf16_t* __restrict__ A,
                                                const bf16_t* __restrict__ BT,
                                                const float* __restrict__ bias,
                                                void* __restrict__ Cout,
                                                int M, int N, int K) {
    __shared__ bf16_t As[128 * 72];
    __shared__ bf16_t Bs[128 * 72];
    const int tid = threadIdx.x;
    const int lane = tid & 63;
    const int wave = tid >> 6;
    const int quad = lane >> 4;
    const int l15 = lane & 15;
    const int wm = (wave >> 1) * 64;
    const int wn = (wave & 1) * 64;
    const size_t rowA0 = (size_t)blockIdx.y * 128;
    const size_t colB0 = (size_t)blockIdx.x * 128;

    const f32x4 fz = {0.f, 0.f, 0.f, 0.f};
    f32x4 acc[4][4];
#pragma unroll
    for (int i = 0; i < 4; i++)
#pragma unroll
        for (int j = 0; j < 4; j++) acc[i][j] = fz;

    for (int k0 = 0; k0 < K; k0 += 64) {
        __syncthreads();
#pragma unroll
        for (int i = 0; i < 4; i++) {
            int c = tid + i * 256;
            int r = c >> 3;
            int kc = (c & 7) * 8;
            uint4 av = *(const uint4*)(A + (rowA0 + r) * (size_t)K + k0 + kc);
            *(uint4*)(&As[r * 72 + kc]) = av;
            uint4 bv = *(const uint4*)(BT + (colB0 + r) * (size_t)K + k0 + kc);
            *(uint4*)(&Bs[r * 72 + kc]) = bv;
        }
        __syncthreads();
#pragma unroll
        for (int kk = 0; kk < 2; kk++) {
            bf16x8 af[4], bfr[4];
#pragma unroll
            for (int i = 0; i < 4; i++)
                af[i] = *(const bf16x8*)(&As[(wm + i * 16 + l15) * 72 + kk * 32 + quad * 8]);
#pragma unroll
            for (int j = 0; j < 4; j++)
                bfr[j] = *(const bf16x8*)(&Bs[(wn + j * 16 + l15) * 72 + kk * 32 + quad * 8]);
#pragma unroll
            for (int i = 0; i < 4; i++)
#pragma unroll
                for (int j = 0; j < 4; j++)
                    acc[i][j] = __builtin_amdgcn_mfma_f32_16x16x32_bf16(af[i], bfr[j], acc[i][j], 0, 0, 0);
        }
    }
    const bool vpath = (OMODE == 2) && (colB0 >= (size_t)(2 * NC));
#pragma unroll
    for (int i = 0; i < 4; i++) {
        size_t row = rowA0 + wm + i * 16 + quad * 4;
#pragma unroll
        for (int j = 0; j < 4; j++) {
            int col = (int)colB0 + wn + j * 16 + l15;
            float bv = bias[col];
            if (vpath) {
                int hh = (col - 2 * NC) >> 6;
                int dd = col & 63;
                int bb = (int)(row >> TSH);
                int tt = (int)row & ((1 << TSH) - 1);
                int tileBase = (bb * NH + hh) * (1 << (TSH - 6)) + (tt >> 6);
                size_t chunkrow = (size_t)tileBase * 4 + (dd >> 4);
                size_t addr = chunkrow * (size_t)N + 2 * NC + (dd & 15) * 64 + (tt & 63);
                bf16x4 vv;
#pragma unroll
                for (int r = 0; r < 4; r++) vv[r] = (bf16_t)(acc[i][j][r] + bv);
                *(bf16x4*)((bf16_t*)Cout + addr) = vv;
            } else {
#pragma unroll
                for (int r = 0; r < 4; r++) {
                    float v = acc[i][j][r] + bv;
                    if (OMODE == 1)
                        ((float*)Cout)[(row + r) * (size_t)N + col] = v;
                    else
                        ((bf16_t*)Cout)[(row + r) * (size_t)N + col] = (bf16_t)v;
                }
            }
        }
    }
}

// ---------------- fused dual-softmax causal attention ----------------
// v11: QBLK=128, 8 waves (512 thr). K/V tiles staged ONCE per 128 q-rows
// (was per 64) -> staging traffic halved; single 16B load+ds_write per thread
// per buffer. Same verified one-barrier double-buffer skeleton as R2/R5.
// Causal mask via runtime limit: zero P where key n > qoff - t*64 (+r).
// Waves 0-3 compute one fully-masked tile at block end (uniform loop, no
// divergent barriers; ~6% extra MFMA).

#define LOADREGS(KB, VCB)                                                            \
    rk0 = *(const uint4*)((KB) + (size_t)(tid >> 3) * 3072 + (tid & 7) * 8);         \
    rv0 = *(const uint4*)((VCB) + (size_t)(tid >> 7) * 3072 + (tid & 127) * 8);

#define STAGE(KS, VS)                                                \
    *(uint4*)(&(KS)[(tid >> 3) * 72 + (tid & 7) * 8]) = rk0;         \
    *(uint4*)(&(VS)[(tid >> 3) * 72 + (tid & 7) * 8]) = rv0;

#define QK(KS, Sj, j)                                                                  \
    Sj = __builtin_amdgcn_mfma_f32_16x16x32_bf16(                                      \
        aq0, *(const bf16x8*)(&(KS)[((j) * 16 + l15) * 72 + quad * 8]), Sj, 0, 0, 0);  \
    Sj = __builtin_amdgcn_mfma_f32_16x16x32_bf16(                                      \
        aq1, *(const bf16x8*)(&(KS)[((j) * 16 + l15) * 72 + 32 + quad * 8]), Sj, 0, 0, 0);

#define EXPJ(Sj, j, BL, LACC)                                           \
    {                                                                   \
        const int n_ = (j) * 16 + l15;                                  \
        _Pragma("unroll") for (int r_ = 0; r_ < 4; r_++) {              \
            float p_ = __expf(Sj[r_] * scale);                          \
            if (n_ > (BL) + r_) p_ = 0.f;                               \
            Sj[r_] = p_;                                                \
            LACC[r_] += p_;                                             \
        }                                                               \
    }

#define PSTORE(Sj, j)                                                   \
    _Pragma("unroll") for (int r_ = 0; r_ < 4; r_++)                    \
        P[(quad * 4 + r_) * 72 + (j) * 16 + l15] = (bf16_t)Sj[r_];

#define PV(VS, Oj, j)                                                                  \
    Oj = __builtin_amdgcn_mfma_f32_16x16x32_bf16(                                      \
        ap0, *(const bf16x8*)(&(VS)[((j) * 16 + l15) * 72 + quad * 8]), Oj, 0, 0, 0);  \
    Oj = __builtin_amdgcn_mfma_f32_16x16x32_bf16(                                      \
        ap1, *(const bf16x8*)(&(VS)[((j) * 16 + l15) * 72 + 32 + quad * 8]), Oj, 0, 0, 0);

#define PROC(KS, VS, BL, LACC, O0, O1, O2, O3)                          \
    {                                                                   \
        f32x4 S0 = fz, S1 = fz, S2 = fz, S3 = fz;                       \
        __builtin_amdgcn_s_setprio(1);                                  \
        QK(KS, S0, 0) QK(KS, S1, 1) QK(KS, S2, 2) QK(KS, S3, 3)         \
        __builtin_amdgcn_s_setprio(0);                                  \
        EXPJ(S0, 0, BL, LACC) EXPJ(S1, 1, BL, LACC)                     \
        EXPJ(S2, 2, BL, LACC) EXPJ(S3, 3, BL, LACC)                     \
        PSTORE(S0, 0) PSTORE(S1, 1) PSTORE(S2, 2) PSTORE(S3, 3)         \
        __builtin_amdgcn_s_waitcnt(0xc07f); /* lgkmcnt(0) */            \
        __builtin_amdgcn_wave_barrier();                                \
        bf16x8 ap0 = *(const bf16x8*)(&P[l15 * 72 + quad * 8]);         \
        bf16x8 ap1 = *(const bf16x8*)(&P[l15 * 72 + 32 + quad * 8]);    \
        __builtin_amdgcn_s_setprio(1);                                  \
        PV(VS, O0, 0) PV(VS, O1, 1) PV(VS, O2, 2) PV(VS, O3, 3)         \
        __builtin_amdgcn_s_setprio(0);                                  \
    }

#define STORE_O(Oj, Pj, j)                                                            \
    _Pragma("unroll") for (int r_ = 0; r_ < 4; r_++) {                                \
        float v_ = Oj[r_] * lmv[r_] + Pj[r_] * lpv[r_];                               \
        y[(qrow0 + quad * 4 + r_) * NC + h * 64 + (j) * 16 + l15] = (bf16_t)v_;       \
    }

__global__ __launch_bounds__(512, 2) void k_attn11(const bf16_t* __restrict__ qkv,
                                                   const bf16_t* __restrict__ pqkv,
                                                   bf16_t* __restrict__ y) {
    const int qt = (NT / 128 - 1) - blockIdx.x;  // LPT: big blocks first
    const int h = blockIdx.y;
    const int b = blockIdx.z;
    const int TMAX = 2 * qt + 1;  // last main tile index

    __shared__ bf16_t Ks0[64 * 72], Ks1[64 * 72];
    __shared__ bf16_t Vs0[64 * 72], Vs1[64 * 72];
    __shared__ bf16_t Ps[8][16 * 72];

    const int tid = threadIdx.x;
    const int lane = tid & 63;
    const int wave = tid >> 6;       // 0..7
    const int quad = lane >> 4;
    const int l15 = lane & 15;
    const float scale = 0.125f;      // 1/sqrt(64)

    const size_t qrow0 = (size_t)b * NT + (size_t)qt * 128 + wave * 16;
    const int qoff = qt * 128 + wave * 16 + quad * 4;  // q row (within b) of acc slot r=0
    bf16_t* P = Ps[wave];

    const bf16_t* Kmain = qkv + (size_t)(b * NT) * 3072 + NC + h * 64;
    // V chunk-bases inside the qkv/pqkv V-thirds (tile t: +t*4*3072)
    const bf16_t* Vmain = qkv + (size_t)(b * NH + h) * 16 * 4 * 3072 + 2 * NC;
    const bf16_t* Vpre  = pqkv + (size_t)(b * NH + h) * 4 * 3072 + 2 * NC;

    // Q A-fragments, loaded once
    bf16x8 aq0 = *(const bf16x8*)(qkv + (qrow0 + l15) * 3072 + h * 64 + quad * 8);
    bf16x8 aq1 = *(const bf16x8*)(qkv + (qrow0 + l15) * 3072 + h * 64 + 32 + quad * 8);

    const f32x4 fz = {0.f, 0.f, 0.f, 0.f};
    f32x4 Om0 = fz, Om1 = fz, Om2 = fz, Om3 = fz;
    f32x4 Op0 = fz, Op1 = fz, Op2 = fz, Op3 = fz;
    f32x4 Lm = fz, Lp = fz;
    uint4 rk0, rv0;

    // ---- prologue: prefix tile -> buf0; main tile 0 loads in flight ----
    LOADREGS(pqkv + (size_t)(b * NTP) * 3072 + NC + h * 64, Vpre)
    STAGE(Ks0, Vs0)
    LOADREGS(Kmain, Vmain)  // main tile 0, lands during prefix PROC
    __syncthreads();        // buf0 visible
    PROC(Ks0, Vs0, qoff, Lp, Op0, Op1, Op2, Op3)  // prefix keys 0..63 vs row qoff
    STAGE(Ks1, Vs1)         // main tile 0 -> buf1 (nobody read buf1 yet)
    LOADREGS(Kmain + (size_t)64 * 3072, Vmain + 4 * 3072)  // main tile 1 (TMAX>=1 always)

    // ---- main causal tiles: ONE barrier per tile ----
    // main tile t lives in buf[(t+1)&1]; STAGE at iter t writes buf[t&1] (tile t+1)
    for (int t = 0; t <= TMAX; t++) {
        __syncthreads();  // buf[(t+1)&1] visible; all reads of buf[t&1] done
        bf16_t* KSc = (t & 1) ? Ks0 : Ks1;
        bf16_t* VSc = (t & 1) ? Vs0 : Vs1;
        if (t < TMAX) {
            bf16_t* KSn = (t & 1) ? Ks1 : Ks0;
            bf16_t* VSn = (t & 1) ? Vs1 : Vs0;
            STAGE(KSn, VSn)  // tile t+1 (regs loaded at iter t-1 / prologue)
        }
        if (t + 1 < TMAX) {
            LOADREGS(Kmain + ((size_t)(t + 2) * 64) * 3072, Vmain + (size_t)(t + 2) * 4 * 3072)
        }
        PROC(KSc, VSc, qoff - t * 64, Lm, Om0, Om1, Om2, Om3)
    }

    // ---- single end-of-kernel row-sum reductions ----
    f32x4 lmv, lpv;
#pragma unroll
    for (int r = 0; r < 4; r++) {
        float vm = Lm[r], vpr = Lp[r];
#pragma unroll
        for (int off = 1; off < 16; off <<= 1) {
            vm += __shfl_xor(vm, off, 64);
            vpr += __shfl_xor(vpr, off, 64);
        }
        lmv[r] = 1.0f / vm;
        lpv[r] = 1.0f / vpr;
    }

    // ---- combine and store ----
    STORE_O(Om0, Op0, 0) STORE_O(Om1, Op1, 1) STORE_O(Om2, Op2, 2) STORE_O(Om3, Op3, 3)
}

// ---------------- launch ----------------
extern "C" void kernel_launch(void* const* d_in, const int* in_sizes, int n_in,
                              void* d_out, int out_size, void* d_ws, size_t ws_size,
                              hipStream_t stream) {
    (void)in_sizes; (void)n_in; (void)out_size; (void)ws_size;
    const float* x        = (const float*)d_in[0];
    const float* prefix   = (const float*)d_in[1];
    const float* w_attn   = (const float*)d_in[2];
    const float* b_attn   = (const float*)d_in[3];
    const float* w_prefix = (const float*)d_in[4];
    const float* b_prefix = (const float*)d_in[5];
    const float* w_proj   = (const float*)d_in[6];
    const float* b_proj   = (const float*)d_in[7];
    float* out = (float*)d_out;

    char* p = (char*)d_ws;
    auto carve = [&](size_t bytes) {
        char* q = p;
        p += (bytes + 255) & ~(size_t)255;
        return q;
    };
    bf16_t* xb   = (bf16_t*)carve((size_t)NB * NT * NC * 2);        // 16 MB
    bf16_t* pb   = (bf16_t*)carve((size_t)NB * NTP * NC * 2);       // 1 MB
    bf16_t* wTa  = (bf16_t*)carve((size_t)3 * NC * NC * 2);         // 6 MB
    bf16_t* wTp  = (bf16_t*)carve((size_t)3 * NC * NC * 2);         // 6 MB
    bf16_t* wTpr = (bf16_t*)carve((size_t)NC * NC * 2);             // 2 MB
    bf16_t* qkv  = (bf16_t*)carve((size_t)NB * NT * 3 * NC * 2);    // 48 MB (V third = tiled V)
    bf16_t* pqkv = (bf16_t*)carve((size_t)NB * NTP * 3 * NC * 2);   // 3 MB (V third = tiled V)
    bf16_t* yb   = (bf16_t*)carve((size_t)NB * NT * NC * 2);        // 16 MB

    const int n4a = NB * NT * NC / 4, n4b = NB * NTP * NC / 4;
    // fused casts (1 launch)
    k_cast2<<<(n4a + n4b + 255) / 256, 256, 0, stream>>>(x, xb, n4a, prefix, pb, n4b);
    // all weight transposes (1 launch)
    k_transpose3<<<dim3(3 * NC / 32, NC / 32, 3), 256, 0, stream>>>(w_attn, wTa, w_prefix, wTp,
                                                                    w_proj, wTpr);
    // qkv = x @ w_attn + b_attn  (V third stored in transposed tile layout in-place)
    k_gemm_f<2, 10><<<dim3(3 * NC / 128, NB * NT / 128), 256, 0, stream>>>(
        xb, wTa, b_attn, qkv, NB * NT, 3 * NC, NC);
    // pqkv = prefix @ w_prefix + b_prefix
    k_gemm_f<2, 6><<<dim3(3 * NC / 128, NB * NTP / 128), 256, 0, stream>>>(
        pb, wTp, b_prefix, pqkv, NB * NTP, 3 * NC, NC);
    // attention (QBLK=128, 8 waves)
    k_attn11<<<dim3(NT / 128, NH, NB), 512, 0, stream>>>(qkv, pqkv, yb);
    // out = y @ w_proj + b_proj (fp32 out)
    k_gemm_f<1, 6><<<dim3(NC / 128, NB * NT / 128), 256, 0, stream>>>(
        yb, wTpr, b_proj, out, NB * NT, NC, NC);
}

// Round 8
// 298.244 us; speedup vs baseline: 1.2943x; 1.0323x over previous
//
#include <hip/hip_runtime.h>
#include <hip/hip_bf16.h>
#include <cstdint>
#include <cstddef>

typedef __bf16 bf16_t;
typedef bf16_t bf16x8 __attribute__((ext_vector_type(8)));
typedef bf16_t bf16x4 __attribute__((ext_vector_type(4)));
typedef float f32x4 __attribute__((ext_vector_type(4)));

#define NB 8
#define NT 1024
#define NC 1024
#define NH 16
#define ND 64
#define NTP 64

// ---------------- fused cast fp32 -> bf16 for x and prefix (one launch) ----------------
__global__ __launch_bounds__(256) void k_cast2(const float* __restrict__ a, bf16_t* __restrict__ da,
                                               int n4a,
                                               const float* __restrict__ b2, bf16_t* __restrict__ db,
                                               int n4b) {
    int i = blockIdx.x * 256 + threadIdx.x;
    if (i < n4a) {
        float4 f = ((const float4*)a)[i];
        bf16x4 o;
        o[0] = (bf16_t)f.x; o[1] = (bf16_t)f.y; o[2] = (bf16_t)f.z; o[3] = (bf16_t)f.w;
        ((bf16x4*)da)[i] = o;
    } else {
        int j = i - n4a;
        if (j < n4b) {
            float4 f = ((const float4*)b2)[j];
            bf16x4 o;
            o[0] = (bf16_t)f.x; o[1] = (bf16_t)f.y; o[2] = (bf16_t)f.z; o[3] = (bf16_t)f.w;
            ((bf16x4*)db)[j] = o;
        }
    }
}

// ------- all 3 weight transposes (K,N) fp32 -> (N,K) bf16 in ONE launch -------
__global__ __launch_bounds__(256) void k_transpose3(const float* __restrict__ s0, bf16_t* __restrict__ d0,
                                                    const float* __restrict__ s1, bf16_t* __restrict__ d1,
                                                    const float* __restrict__ s2, bf16_t* __restrict__ d2) {
    __shared__ float tile[32][33];
    const int z = blockIdx.z;
    const float* src = (z == 0) ? s0 : (z == 1) ? s1 : s2;
    bf16_t* dst = (z == 0) ? d0 : (z == 1) ? d1 : d2;
    const int N = (z == 2) ? NC : 3 * NC;
    const int K = NC;
    if (z == 2 && blockIdx.x >= 32) return;
    int nt = blockIdx.x, kt = blockIdx.y;
    int tx = threadIdx.x & 31;
    int ty = threadIdx.x >> 5;  // 0..7
#pragma unroll
    for (int i = 0; i < 4; i++) {
        int r = ty + i * 8;
        tile[r][tx] = src[(size_t)(kt * 32 + r) * N + nt * 32 + tx];
    }
    __syncthreads();
#pragma unroll
    for (int i = 0; i < 4; i++) {
        int r = ty + i * 8;
        dst[(size_t)(nt * 32 + r) * K + kt * 32 + tx] = (bf16_t)tile[tx][r];
    }
}

// ======== shared 128x128 GEMM body (proven 2-barrier reg-staged path) ========
// Computes one 128x128 C tile; qkv-mode V remap handled by caller lambda-free flags.

// ---------------- merged qkv + pqkv GEMM (grid 24 x 68, XCD-swizzled) ----------------
// by<64: qkv = xb @ wTa + b_attn (M=8192, TSH=10). by>=64: pqkv = pb @ wTp + b_prefix
// (M=512, TSH=6). cols>=2048 (V third) stored via bijective transposed-tile remap
// (fuses k_vT; attention reads V through the same map).
__global__ __launch_bounds__(256) void k_gemm_qkv(const bf16_t* __restrict__ xb,
                                                  const bf16_t* __restrict__ pb,
                                                  const bf16_t* __restrict__ wTa,
                                                  const bf16_t* __restrict__ wTp,
                                                  const float* __restrict__ b_attn,
                                                  const float* __restrict__ b_prefix,
                                                  bf16_t* __restrict__ qkv,
                                                  bf16_t* __restrict__ pqkv) {
    // T1 XCD swizzle: nwg = 24*68 = 1632 (%8==0). XCD x gets contiguous work chunk.
    const int nwg = 24 * 68;
    const int flat = blockIdx.y * 24 + blockIdx.x;
    const int wgid = (flat & 7) * (nwg >> 3) + (flat >> 3);
    const int bx = wgid % 24;
    const int byw = wgid / 24;
    const bool pre = (byw >= 64);
    const bf16_t* A = pre ? pb : xb;
    const bf16_t* BT = pre ? wTp : wTa;
    const float* bias = pre ? b_prefix : b_attn;
    bf16_t* Cout = pre ? pqkv : qkv;
    const int tsh = pre ? 6 : 10;
    const size_t rowA0 = (size_t)(pre ? (byw - 64) : byw) * 128;
    const size_t colB0 = (size_t)bx * 128;
    const int K = NC, N = 3 * NC;

    __shared__ bf16_t As[128 * 72];
    __shared__ bf16_t Bs[128 * 72];
    const int tid = threadIdx.x;
    const int lane = tid & 63;
    const int wave = tid >> 6;
    const int quad = lane >> 4;
    const int l15 = lane & 15;
    const int wm = (wave >> 1) * 64;
    const int wn = (wave & 1) * 64;

    const f32x4 fz = {0.f, 0.f, 0.f, 0.f};
    f32x4 acc[4][4];
#pragma unroll
    for (int i = 0; i < 4; i++)
#pragma unroll
        for (int j = 0; j < 4; j++) acc[i][j] = fz;

    for (int k0 = 0; k0 < K; k0 += 64) {
        __syncthreads();
#pragma unroll
        for (int i = 0; i < 4; i++) {
            int c = tid + i * 256;
            int r = c >> 3;
            int kc = (c & 7) * 8;
            uint4 av = *(const uint4*)(A + (rowA0 + r) * (size_t)K + k0 + kc);
            *(uint4*)(&As[r * 72 + kc]) = av;
            uint4 bv = *(const uint4*)(BT + (colB0 + r) * (size_t)K + k0 + kc);
            *(uint4*)(&Bs[r * 72 + kc]) = bv;
        }
        __syncthreads();
#pragma unroll
        for (int kk = 0; kk < 2; kk++) {
            bf16x8 af[4], bfr[4];
#pragma unroll
            for (int i = 0; i < 4; i++)
                af[i] = *(const bf16x8*)(&As[(wm + i * 16 + l15) * 72 + kk * 32 + quad * 8]);
#pragma unroll
            for (int j = 0; j < 4; j++)
                bfr[j] = *(const bf16x8*)(&Bs[(wn + j * 16 + l15) * 72 + kk * 32 + quad * 8]);
#pragma unroll
            for (int i = 0; i < 4; i++)
#pragma unroll
                for (int j = 0; j < 4; j++)
                    acc[i][j] = __builtin_amdgcn_mfma_f32_16x16x32_bf16(af[i], bfr[j], acc[i][j], 0, 0, 0);
        }
    }
    const bool vpath = (colB0 >= (size_t)(2 * NC));
#pragma unroll
    for (int i = 0; i < 4; i++) {
        size_t row = rowA0 + wm + i * 16 + quad * 4;
#pragma unroll
        for (int j = 0; j < 4; j++) {
            int col = (int)colB0 + wn + j * 16 + l15;
            float bv = bias[col];
            if (vpath) {
                int hh = (col - 2 * NC) >> 6;
                int dd = col & 63;
                int bb = (int)(row >> tsh);
                int tt = (int)row & ((1 << tsh) - 1);
                int tileBase = (bb * NH + hh) * (1 << (tsh - 6)) + (tt >> 6);
                size_t chunkrow = (size_t)tileBase * 4 + (dd >> 4);
                size_t addr = chunkrow * (size_t)N + 2 * NC + (dd & 15) * 64 + (tt & 63);
                bf16x4 vv;
#pragma unroll
                for (int r = 0; r < 4; r++) vv[r] = (bf16_t)(acc[i][j][r] + bv);
                *(bf16x4*)(Cout + addr) = vv;
            } else {
#pragma unroll
                for (int r = 0; r < 4; r++) {
                    float v = acc[i][j][r] + bv;
                    Cout[(row + r) * (size_t)N + col] = (bf16_t)v;
                }
            }
        }
    }
}

// ---------------- proj GEMM: out(f32) = yb @ wTpr + b_proj (XCD-swizzled) ----------------
__global__ __launch_bounds__(256) void k_gemm_proj(const bf16_t* __restrict__ A,
                                                   const bf16_t* __restrict__ BT,
                                                   const float* __restrict__ bias,
                                                   float* __restrict__ Cout,
                                                   int M, int N, int K) {
    // T1 XCD swizzle (nwg = gridDim.x*gridDim.y, both launches %8==0)
    const int nwg = gridDim.x * gridDim.y;
    const int flat = blockIdx.y * gridDim.x + blockIdx.x;
    const int wgid = (flat & 7) * (nwg >> 3) + (flat >> 3);
    const int bx = wgid % gridDim.x;
    const int byw = wgid / gridDim.x;
    const size_t rowA0 = (size_t)byw * 128;
    const size_t colB0 = (size_t)bx * 128;

    __shared__ bf16_t As[128 * 72];
    __shared__ bf16_t Bs[128 * 72];
    const int tid = threadIdx.x;
    const int lane = tid & 63;
    const int wave = tid >> 6;
    const int quad = lane >> 4;
    const int l15 = lane & 15;
    const int wm = (wave >> 1) * 64;
    const int wn = (wave & 1) * 64;

    const f32x4 fz = {0.f, 0.f, 0.f, 0.f};
    f32x4 acc[4][4];
#pragma unroll
    for (int i = 0; i < 4; i++)
#pragma unroll
        for (int j = 0; j < 4; j++) acc[i][j] = fz;

    for (int k0 = 0; k0 < K; k0 += 64) {
        __syncthreads();
#pragma unroll
        for (int i = 0; i < 4; i++) {
            int c = tid + i * 256;
            int r = c >> 3;
            int kc = (c & 7) * 8;
            uint4 av = *(const uint4*)(A + (rowA0 + r) * (size_t)K + k0 + kc);
            *(uint4*)(&As[r * 72 + kc]) = av;
            uint4 bv = *(const uint4*)(BT + (colB0 + r) * (size_t)K + k0 + kc);
            *(uint4*)(&Bs[r * 72 + kc]) = bv;
        }
        __syncthreads();
#pragma unroll
        for (int kk = 0; kk < 2; kk++) {
            bf16x8 af[4], bfr[4];
#pragma unroll
            for (int i = 0; i < 4; i++)
                af[i] = *(const bf16x8*)(&As[(wm + i * 16 + l15) * 72 + kk * 32 + quad * 8]);
#pragma unroll
            for (int j = 0; j < 4; j++)
                bfr[j] = *(const bf16x8*)(&Bs[(wn + j * 16 + l15) * 72 + kk * 32 + quad * 8]);
#pragma unroll
            for (int i = 0; i < 4; i++)
#pragma unroll
                for (int j = 0; j < 4; j++)
                    acc[i][j] = __builtin_amdgcn_mfma_f32_16x16x32_bf16(af[i], bfr[j], acc[i][j], 0, 0, 0);
        }
    }
#pragma unroll
    for (int i = 0; i < 4; i++) {
        size_t row = rowA0 + wm + i * 16 + quad * 4;
#pragma unroll
        for (int j = 0; j < 4; j++) {
            int col = (int)colB0 + wn + j * 16 + l15;
            float bv = bias[col];
#pragma unroll
            for (int r = 0; r < 4; r++)
                Cout[(row + r) * (size_t)N + col] = acc[i][j][r] + bv;
        }
    }
}

// ---------------- fused dual-softmax causal attention (R6 v11 + XCD swizzle) ------------
#define LOADREGS(KB, VCB)                                                            \
    rk0 = *(const uint4*)((KB) + (size_t)(tid >> 3) * 3072 + (tid & 7) * 8);         \
    rv0 = *(const uint4*)((VCB) + (size_t)(tid >> 7) * 3072 + (tid & 127) * 8);

#define STAGE(KS, VS)                                                \
    *(uint4*)(&(KS)[(tid >> 3) * 72 + (tid & 7) * 8]) = rk0;         \
    *(uint4*)(&(VS)[(tid >> 3) * 72 + (tid & 7) * 8]) = rv0;

#define QK(KS, Sj, j)                                                                  \
    Sj = __builtin_amdgcn_mfma_f32_16x16x32_bf16(                                      \
        aq0, *(const bf16x8*)(&(KS)[((j) * 16 + l15) * 72 + quad * 8]), Sj, 0, 0, 0);  \
    Sj = __builtin_amdgcn_mfma_f32_16x16x32_bf16(                                      \
        aq1, *(const bf16x8*)(&(KS)[((j) * 16 + l15) * 72 + 32 + quad * 8]), Sj, 0, 0, 0);

#define EXPJ(Sj, j, BL, LACC)                                           \
    {                                                                   \
        const int n_ = (j) * 16 + l15;                                  \
        _Pragma("unroll") for (int r_ = 0; r_ < 4; r_++) {              \
            float p_ = __expf(Sj[r_] * scale);                          \
            if (n_ > (BL) + r_) p_ = 0.f;                               \
            Sj[r_] = p_;                                                \
            LACC[r_] += p_;                                             \
        }                                                               \
    }

#define PSTORE(Sj, j)                                                   \
    _Pragma("unroll") for (int r_ = 0; r_ < 4; r_++)                    \
        P[(quad * 4 + r_) * 72 + (j) * 16 + l15] = (bf16_t)Sj[r_];

#define PV(VS, Oj, j)                                                                  \
    Oj = __builtin_amdgcn_mfma_f32_16x16x32_bf16(                                      \
        ap0, *(const bf16x8*)(&(VS)[((j) * 16 + l15) * 72 + quad * 8]), Oj, 0, 0, 0);  \
    Oj = __builtin_amdgcn_mfma_f32_16x16x32_bf16(                                      \
        ap1, *(const bf16x8*)(&(VS)[((j) * 16 + l15) * 72 + 32 + quad * 8]), Oj, 0, 0, 0);

#define PROC(KS, VS, BL, LACC, O0, O1, O2, O3)                          \
    {                                                                   \
        f32x4 S0 = fz, S1 = fz, S2 = fz, S3 = fz;                       \
        __builtin_amdgcn_s_setprio(1);                                  \
        QK(KS, S0, 0) QK(KS, S1, 1) QK(KS, S2, 2) QK(KS, S3, 3)         \
        __builtin_amdgcn_s_setprio(0);                                  \
        EXPJ(S0, 0, BL, LACC) EXPJ(S1, 1, BL, LACC)                     \
        EXPJ(S2, 2, BL, LACC) EXPJ(S3, 3, BL, LACC)                     \
        PSTORE(S0, 0) PSTORE(S1, 1) PSTORE(S2, 2) PSTORE(S3, 3)         \
        __builtin_amdgcn_s_waitcnt(0xc07f); /* lgkmcnt(0) */            \
        __builtin_amdgcn_wave_barrier();                                \
        bf16x8 ap0 = *(const bf16x8*)(&P[l15 * 72 + quad * 8]);         \
        bf16x8 ap1 = *(const bf16x8*)(&P[l15 * 72 + 32 + quad * 8]);    \
        __builtin_amdgcn_s_setprio(1);                                  \
        PV(VS, O0, 0) PV(VS, O1, 1) PV(VS, O2, 2) PV(VS, O3, 3)         \
        __builtin_amdgcn_s_setprio(0);                                  \
    }

#define STORE_O(Oj, Pj, j)                                                            \
    _Pragma("unroll") for (int r_ = 0; r_ < 4; r_++) {                                \
        float v_ = Oj[r_] * lmv[r_] + Pj[r_] * lpv[r_];                               \
        y[(qrow0 + quad * 4 + r_) * NC + h * 64 + (j) * 16 + l15] = (bf16_t)v_;       \
    }

__global__ __launch_bounds__(512, 2) void k_attn11(const bf16_t* __restrict__ qkv,
                                                   const bf16_t* __restrict__ pqkv,
                                                   bf16_t* __restrict__ y) {
    // T1 XCD swizzle over flat grid (8,16,8) = 1024 blocks. XCD0 gets b=0 entirely
    // (K/V working set 16 heads x 256KB = 4MB = one L2); LPT preserved: first
    // dispatched blocks on each XCD map to x=0 (largest qt).
    const int flat = (int)blockIdx.x + 8 * ((int)blockIdx.y + 16 * (int)blockIdx.z);
    const int wgid = (flat & 7) * 128 + (flat >> 3);
    const int qt = (NT / 128 - 1) - (wgid & 7);
    const int h = (wgid >> 3) & 15;
    const int b = wgid >> 7;
    const int TMAX = 2 * qt + 1;  // last main tile index

    __shared__ bf16_t Ks0[64 * 72], Ks1[64 * 72];
    __shared__ bf16_t Vs0[64 * 72], Vs1[64 * 72];
    __shared__ bf16_t Ps[8][16 * 72];

    const int tid = threadIdx.x;
    const int lane = tid & 63;
    const int wave = tid >> 6;       // 0..7
    const int quad = lane >> 4;
    const int l15 = lane & 15;
    const float scale = 0.125f;      // 1/sqrt(64)

    const size_t qrow0 = (size_t)b * NT + (size_t)qt * 128 + wave * 16;
    const int qoff = qt * 128 + wave * 16 + quad * 4;  // q row (within b) of acc slot r=0
    bf16_t* P = Ps[wave];

    const bf16_t* Kmain = qkv + (size_t)(b * NT) * 3072 + NC + h * 64;
    const bf16_t* Vmain = qkv + (size_t)(b * NH + h) * 16 * 4 * 3072 + 2 * NC;
    const bf16_t* Vpre  = pqkv + (size_t)(b * NH + h) * 4 * 3072 + 2 * NC;

    bf16x8 aq0 = *(const bf16x8*)(qkv + (qrow0 + l15) * 3072 + h * 64 + quad * 8);
    bf16x8 aq1 = *(const bf16x8*)(qkv + (qrow0 + l15) * 3072 + h * 64 + 32 + quad * 8);

    const f32x4 fz = {0.f, 0.f, 0.f, 0.f};
    f32x4 Om0 = fz, Om1 = fz, Om2 = fz, Om3 = fz;
    f32x4 Op0 = fz, Op1 = fz, Op2 = fz, Op3 = fz;
    f32x4 Lm = fz, Lp = fz;
    uint4 rk0, rv0;

    LOADREGS(pqkv + (size_t)(b * NTP) * 3072 + NC + h * 64, Vpre)
    STAGE(Ks0, Vs0)
    LOADREGS(Kmain, Vmain)
    __syncthreads();
    PROC(Ks0, Vs0, qoff, Lp, Op0, Op1, Op2, Op3)
    STAGE(Ks1, Vs1)
    LOADREGS(Kmain + (size_t)64 * 3072, Vmain + 4 * 3072)

    for (int t = 0; t <= TMAX; t++) {
        __syncthreads();
        bf16_t* KSc = (t & 1) ? Ks0 : Ks1;
        bf16_t* VSc = (t & 1) ? Vs0 : Vs1;
        if (t < TMAX) {
            bf16_t* KSn = (t & 1) ? Ks1 : Ks0;
            bf16_t* VSn = (t & 1) ? Vs1 : Vs0;
            STAGE(KSn, VSn)
        }
        if (t + 1 < TMAX) {
            LOADREGS(Kmain + ((size_t)(t + 2) * 64) * 3072, Vmain + (size_t)(t + 2) * 4 * 3072)
        }
        PROC(KSc, VSc, qoff - t * 64, Lm, Om0, Om1, Om2, Om3)
    }

    f32x4 lmv, lpv;
#pragma unroll
    for (int r = 0; r < 4; r++) {
        float vm = Lm[r], vpr = Lp[r];
#pragma unroll
        for (int off = 1; off < 16; off <<= 1) {
            vm += __shfl_xor(vm, off, 64);
            vpr += __shfl_xor(vpr, off, 64);
        }
        lmv[r] = 1.0f / vm;
        lpv[r] = 1.0f / vpr;
    }

    STORE_O(Om0, Op0, 0) STORE_O(Om1, Op1, 1) STORE_O(Om2, Op2, 2) STORE_O(Om3, Op3, 3)
}

// ---------------- launch ----------------
extern "C" void kernel_launch(void* const* d_in, const int* in_sizes, int n_in,
                              void* d_out, int out_size, void* d_ws, size_t ws_size,
                              hipStream_t stream) {
    (void)in_sizes; (void)n_in; (void)out_size; (void)ws_size;
    const float* x        = (const float*)d_in[0];
    const float* prefix   = (const float*)d_in[1];
    const float* w_attn   = (const float*)d_in[2];
    const float* b_attn   = (const float*)d_in[3];
    const float* w_prefix = (const float*)d_in[4];
    const float* b_prefix = (const float*)d_in[5];
    const float* w_proj   = (const float*)d_in[6];
    const float* b_proj   = (const float*)d_in[7];
    float* out = (float*)d_out;

    char* p = (char*)d_ws;
    auto carve = [&](size_t bytes) {
        char* q = p;
        p += (bytes + 255) & ~(size_t)255;
        return q;
    };
    bf16_t* xb   = (bf16_t*)carve((size_t)NB * NT * NC * 2);        // 16 MB
    bf16_t* pb   = (bf16_t*)carve((size_t)NB * NTP * NC * 2);       // 1 MB
    bf16_t* wTa  = (bf16_t*)carve((size_t)3 * NC * NC * 2);         // 6 MB
    bf16_t* wTp  = (bf16_t*)carve((size_t)3 * NC * NC * 2);         // 6 MB
    bf16_t* wTpr = (bf16_t*)carve((size_t)NC * NC * 2);             // 2 MB
    bf16_t* qkv  = (bf16_t*)carve((size_t)NB * NT * 3 * NC * 2);    // 48 MB (V third = tiled V)
    bf16_t* pqkv = (bf16_t*)carve((size_t)NB * NTP * 3 * NC * 2);   // 3 MB (V third = tiled V)
    bf16_t* yb   = (bf16_t*)carve((size_t)NB * NT * NC * 2);        // 16 MB

    const int n4a = NB * NT * NC / 4, n4b = NB * NTP * NC / 4;
    k_cast2<<<(n4a + n4b + 255) / 256, 256, 0, stream>>>(x, xb, n4a, prefix, pb, n4b);
    k_transpose3<<<dim3(3 * NC / 32, NC / 32, 3), 256, 0, stream>>>(w_attn, wTa, w_prefix, wTp,
                                                                    w_proj, wTpr);
    // merged qkv + pqkv GEMM (XCD-swizzled; V thirds -> transposed tile layout in-place)
    k_gemm_qkv<<<dim3(24, 68), 256, 0, stream>>>(xb, pb, wTa, wTp, b_attn, b_prefix, qkv, pqkv);
    // attention (QBLK=128, 8 waves, XCD-swizzled)
    k_attn11<<<dim3(NT / 128, NH, NB), 512, 0, stream>>>(qkv, pqkv, yb);
    // out = y @ w_proj + b_proj (fp32 out, XCD-swizzled)
    k_gemm_proj<<<dim3(NC / 128, NB * NT / 128), 256, 0, stream>>>(
        yb, wTpr, b_proj, out, NB * NT, NC, NC);
}